// Round 11
// baseline (448.452 us; speedup 1.0000x reference)
//
#include <hip/hip_runtime.h>
#include <math.h>

#define N 2048
#define D 256
#define H 8
#define DK 32
#define L 4
#define DFF 1024
#define NEDGE 5
#define JC 8  // attention j-chunks (flash-decode split)

typedef short short8 __attribute__((ext_vector_type(8)));
typedef float floatx4 __attribute__((ext_vector_type(4)));

// Q pre-scale: 1/sqrt(DK) * log2(e)  (attention uses raw v_exp_f32 = exp2)
#define QSCALE 0.25503485657f
#define LOG2E 1.4426950408889634f

#define MFMA(a, b, c) __builtin_amdgcn_mfma_f32_16x16x32_bf16(a, b, c, 0, 0, 0)

#define AB_STR 280   // (280*2/4)%32 = 12-bank row stride -> 2-way alias (free)
#define PB_STR 72
#define HS_STR 1048  // same 12-bank residue as AB_STR

__device__ __forceinline__ unsigned short f2bf(float f) {
  unsigned int u = __float_as_uint(f);
  u += 0x7fffu + ((u >> 16) & 1u);
  return (unsigned short)(u >> 16);
}

__device__ __forceinline__ float exp2_hw(float x) {
  float r;
  asm("v_exp_f32 %0, %1" : "=v"(r) : "v"(x));
  return r;
}

__device__ __forceinline__ unsigned int cvt_pk_bf16(float lo, float hi) {
  unsigned int r;
  asm("v_cvt_pk_bf16_f32 %0, %1, %2" : "=v"(r) : "v"(lo), "v"(hi));
  return r;
}

__device__ __forceinline__ void async16(unsigned short* lds, const unsigned short* g) {
  __builtin_amdgcn_global_load_lds(
      (const __attribute__((address_space(1))) unsigned int*)g,
      (__attribute__((address_space(3))) unsigned int*)lds, 16, 0, 0);
}

// ---- setup: e8 pack + weight transposes + WrT fp32 ------------------------
__global__ __launch_bounds__(256) void k_setup(
    const int* __restrict__ eidx, unsigned int* __restrict__ e8,
    const float* __restrict__ Wq, const float* __restrict__ Wk,
    const float* __restrict__ Wv, const float* __restrict__ Wo,
    const float* __restrict__ W1, const float* __restrict__ W2,
    const float* __restrict__ Wr,
    unsigned short* __restrict__ wqkvb, unsigned short* __restrict__ wob,
    unsigned short* __restrict__ w1b, unsigned short* __restrict__ w2b,
    float* __restrict__ WrT) {
  __shared__ float t[32][33];
  const int blk = blockIdx.x;
  const int tid = threadIdx.x;
  if (blk < 4096) {
    int i = blk * 256 + tid;  // word i = cols 4i..4i+3 of row i/512
    int4 v = ((const int4*)eidx)[i];
    e8[i] = (unsigned int)(v.x & 0xff) | ((unsigned int)(v.y & 0xff) << 8) |
            ((unsigned int)(v.z & 0xff) << 16) | ((unsigned int)(v.w & 0xff) << 24);
    return;
  }
  const int tx = tid & 31, ty = tid >> 5;
  if (blk >= 7168) {  // Wr (512,256) fp32 -> WrT (256,512) fp32
    int b5 = blk - 7168, bx = b5 & 7, by = b5 >> 3;
#pragma unroll
    for (int i = 0; i < 32; i += 8)
      t[ty + i][tx] = Wr[(size_t)(by * 32 + ty + i) * D + bx * 32 + tx];
    __syncthreads();
#pragma unroll
    for (int i = 0; i < 32; i += 8)
      WrT[(size_t)(bx * 32 + ty + i) * 512 + by * 32 + tx] = t[tx][ty + i];
    return;
  }
  const float* s;
  unsigned short* d;
  int rowOff, K_, N_, bx, by;
  if (blk < 5120) {
    int b2 = blk - 4096, z = b2 >> 6, rem = b2 & 63;
    int which = z >> 2, l = z & 3;
    s = (which == 0 ? Wq : which == 1 ? Wk : which == 2 ? Wv : Wo) + (size_t)l * D * D;
    if (which < 3) { d = wqkvb + (size_t)l * 768 * D; rowOff = which * 256; }
    else           { d = wob + (size_t)l * D * D;     rowOff = 0; }
    K_ = D; N_ = D; bx = rem & 7; by = rem >> 3;
  } else if (blk < 6144) {
    int b3 = blk - 5120, l = b3 >> 8, rem = b3 & 255;
    s = W1 + (size_t)l * D * DFF; d = w1b + (size_t)l * DFF * D; rowOff = 0;
    K_ = D; N_ = DFF; bx = rem & 31; by = rem >> 5;
  } else {
    int b4 = blk - 6144, l = b4 >> 8, rem = b4 & 255;
    s = W2 + (size_t)l * DFF * D; d = w2b + (size_t)l * D * DFF; rowOff = 0;
    K_ = DFF; N_ = D; bx = rem & 7; by = rem >> 3;
  }
  int n0 = bx * 32, k0 = by * 32;
#pragma unroll
  for (int i = 0; i < 32; i += 8) t[ty + i][tx] = s[(size_t)(k0 + ty + i) * N_ + n0 + tx];
  __syncthreads();
#pragma unroll
  for (int i = 0; i < 32; i += 8)
    d[(size_t)(rowOff + n0 + ty + i) * K_ + k0 + tx] = f2bf(t[tx][ty + i]);
}

// ---- qkv tail for 8-wave/16-row blocks ------------------------------------
__device__ __forceinline__ void qkv_from_Ab8(
    const unsigned short* Ab, const unsigned short* __restrict__ wqkv,
    unsigned short* __restrict__ qb, unsigned short* __restrict__ kb,
    unsigned short* __restrict__ vtb, int r0, int w, int quad, int c16) {
  short8 af[8];
#pragma unroll
  for (int k = 0; k < 8; ++k)
    af[k] = *(const short8*)&Ab[c16 * AB_STR + k * 32 + quad * 8];
#pragma unroll
  for (int tp = 0; tp < 3; ++tp) {
    const int cb0 = (w * 6 + tp * 2) * 16 + c16;
    const int cb1 = cb0 + 16;
    const unsigned short* B0 = wqkv + (size_t)cb0 * D + quad * 8;
    const unsigned short* B1 = wqkv + (size_t)cb1 * D + quad * 8;
    floatx4 a0 = {0.f, 0.f, 0.f, 0.f}, a1 = {0.f, 0.f, 0.f, 0.f};
#pragma unroll
    for (int k = 0; k < 8; ++k) {
      a0 = MFMA(af[k], *(const short8*)(B0 + k * 32), a0);
      a1 = MFMA(af[k], *(const short8*)(B1 + k * 32), a1);
    }
#pragma unroll
    for (int e = 0; e < 4; ++e) {
      const int grow = r0 + quad * 4 + e;
#pragma unroll
      for (int half = 0; half < 2; ++half) {
        int gc = half ? cb1 : cb0;
        float v = half ? a1[e] : a0[e];
        if (gc < 256)      qb[(size_t)grow * D + gc] = f2bf(v * QSCALE);
        else if (gc < 512) kb[(size_t)grow * D + (gc - 256)] = f2bf(v);
        else               vtb[(size_t)(gc - 512) * N + grow] = f2bf(v);
      }
    }
  }
}

// ---- embed + layer-0 QKV --------------------------------------------------
__global__ __launch_bounds__(512) void k_embed_qkv(
    const int* __restrict__ nt, const float* __restrict__ emb,
    const unsigned short* __restrict__ wqkv0, float* __restrict__ x,
    unsigned short* __restrict__ qb, unsigned short* __restrict__ kb,
    unsigned short* __restrict__ vtb) {
  __shared__ __align__(16) unsigned short Ab[16 * AB_STR];
  const int tid = threadIdx.x;
  const int w = tid >> 6, lane = tid & 63, quad = lane >> 4, c16 = lane & 15;
  const int r0 = blockIdx.x * 16;
  {
    const int r = tid >> 5, cb = (tid & 31) * 8;
    const int ty = nt[r0 + r];
    float4 a = *(const float4*)&emb[(size_t)ty * D + cb];
    float4 b = *(const float4*)&emb[(size_t)ty * D + cb + 4];
    *(float4*)&x[(size_t)(r0 + r) * D + cb] = a;
    *(float4*)&x[(size_t)(r0 + r) * D + cb + 4] = b;
    Ab[r * AB_STR + cb + 0] = f2bf(a.x); Ab[r * AB_STR + cb + 1] = f2bf(a.y);
    Ab[r * AB_STR + cb + 2] = f2bf(a.z); Ab[r * AB_STR + cb + 3] = f2bf(a.w);
    Ab[r * AB_STR + cb + 4] = f2bf(b.x); Ab[r * AB_STR + cb + 5] = f2bf(b.y);
    Ab[r * AB_STR + cb + 6] = f2bf(b.z); Ab[r * AB_STR + cb + 7] = f2bf(b.w);
  }
  __syncthreads();
  qkv_from_Ab8(Ab, wqkv0, qb, kb, vtb, r0, w, quad, c16);
}

// ---- MFMA flash attention: QBLK=32, JC=8, m=0, contiguous-P ---------------
__global__ __launch_bounds__(512) void k_attn(const unsigned short* __restrict__ qb,
                                              const unsigned short* __restrict__ kb,
                                              const unsigned short* __restrict__ vt,
                                              const unsigned int* __restrict__ e8,
                                              const float* __restrict__ eb,
                                              float* __restrict__ Opart,
                                              float* __restrict__ lpart) {
  __shared__ __align__(16) unsigned short Pb[H][32 * PB_STR];
  __shared__ float ebh[H][NEDGE];
  __shared__ unsigned int e8s[32][65];
  const int tid = threadIdx.x;
  const int h = tid >> 6;
  const int lane = tid & 63;
  const int quad = lane >> 4;
  const int c16 = lane & 15;
  const int r0 = blockIdx.x * 32;
  const int jc = blockIdx.y;

  if (tid < NEDGE * H) ebh[tid % H][tid / H] = eb[tid] * LOG2E;
  for (int i = tid; i < 32 * 64; i += 512) {
    int r = i >> 6, ww = i & 63;
    e8s[r][ww] = e8[(size_t)(r0 + r) * (N / 4) + jc * 64 + ww];
  }
  __syncthreads();

  short8 aqA = *(const short8*)&qb[(size_t)(r0 + c16) * D + h * DK + quad * 8];
  short8 aqB = *(const short8*)&qb[(size_t)(r0 + 16 + c16) * D + h * DK + quad * 8];

  float lrowA[4] = {0.f, 0.f, 0.f, 0.f};
  float lrowB[4] = {0.f, 0.f, 0.f, 0.f};
  floatx4 O0A = {0.f, 0.f, 0.f, 0.f}, O1A = {0.f, 0.f, 0.f, 0.f};
  floatx4 O0B = {0.f, 0.f, 0.f, 0.f}, O1B = {0.f, 0.f, 0.f, 0.f};

  for (int g = 0; g < (N / JC) / 64; ++g) {
    const int j0 = jc * (N / JC) + g * 64;
    short8 bk[4];
#pragma unroll
    for (int t = 0; t < 4; ++t)
      bk[t] = *(const short8*)&kb[(size_t)(j0 + c16 * 4 + t) * D + h * DK + quad * 8];
    {
      unsigned int wrd[4];
#pragma unroll
      for (int e = 0; e < 4; ++e) wrd[e] = e8s[quad * 4 + e][g * 16 + c16];
      floatx4 Sc[4];
#pragma unroll
      for (int t = 0; t < 4; ++t) {
        floatx4 cbv;
#pragma unroll
        for (int e = 0; e < 4; ++e) cbv[e] = ebh[h][(wrd[e] >> (8 * t)) & 0xff];
        Sc[t] = MFMA(aqA, bk[t], cbv);
      }
      float p[4][4];
#pragma unroll
      for (int e = 0; e < 4; ++e) {
#pragma unroll
        for (int t = 0; t < 4; ++t) p[t][e] = exp2_hw(Sc[t][e]);
        lrowA[e] += (p[0][e] + p[1][e]) + (p[2][e] + p[3][e]);
      }
#pragma unroll
      for (int e = 0; e < 4; ++e) {
        uint2 u;
        u.x = cvt_pk_bf16(p[0][e], p[1][e]);
        u.y = cvt_pk_bf16(p[2][e], p[3][e]);
        *(uint2*)&Pb[h][(quad * 4 + e) * PB_STR + c16 * 4] = u;
      }
    }
    {
      unsigned int wrd[4];
#pragma unroll
      for (int e = 0; e < 4; ++e) wrd[e] = e8s[16 + quad * 4 + e][g * 16 + c16];
      floatx4 Sc[4];
#pragma unroll
      for (int t = 0; t < 4; ++t) {
        floatx4 cbv;
#pragma unroll
        for (int e = 0; e < 4; ++e) cbv[e] = ebh[h][(wrd[e] >> (8 * t)) & 0xff];
        Sc[t] = MFMA(aqB, bk[t], cbv);
      }
      float p[4][4];
#pragma unroll
      for (int e = 0; e < 4; ++e) {
#pragma unroll
        for (int t = 0; t < 4; ++t) p[t][e] = exp2_hw(Sc[t][e]);
        lrowB[e] += (p[0][e] + p[1][e]) + (p[2][e] + p[3][e]);
      }
#pragma unroll
      for (int e = 0; e < 4; ++e) {
        uint2 u;
        u.x = cvt_pk_bf16(p[0][e], p[1][e]);
        u.y = cvt_pk_bf16(p[2][e], p[3][e]);
        *(uint2*)&Pb[h][(16 + quad * 4 + e) * PB_STR + c16 * 4] = u;
      }
    }
    asm volatile("" ::: "memory");
#pragma unroll
    for (int jj = 0; jj < 2; ++jj) {
      short8 apA = *(const short8*)&Pb[h][c16 * PB_STR + jj * 32 + quad * 8];
      short8 apB = *(const short8*)&Pb[h][(16 + c16) * PB_STR + jj * 32 + quad * 8];
      short8 bv0 = *(const short8*)&vt[(size_t)(h * DK + c16) * N + j0 + jj * 32 + quad * 8];
      short8 bv1 = *(const short8*)&vt[(size_t)(h * DK + 16 + c16) * N + j0 + jj * 32 + quad * 8];
      O0A = MFMA(apA, bv0, O0A); O1A = MFMA(apA, bv1, O1A);
      O0B = MFMA(apB, bv0, O0B); O1B = MFMA(apB, bv1, O1B);
    }
    asm volatile("" ::: "memory");
  }

#pragma unroll
  for (int e = 0; e < 4; ++e) {
    float va = lrowA[e], vb = lrowB[e];
    va += __shfl_xor(va, 1); va += __shfl_xor(va, 2);
    va += __shfl_xor(va, 4); va += __shfl_xor(va, 8);
    vb += __shfl_xor(vb, 1); vb += __shfl_xor(vb, 2);
    vb += __shfl_xor(vb, 4); vb += __shfl_xor(vb, 8);
    lrowA[e] = va; lrowB[e] = vb;
  }
#pragma unroll
  for (int e = 0; e < 4; ++e) {
    int rowA = r0 + quad * 4 + e, rowB = rowA + 16;
    size_t obA = ((size_t)jc * N + rowA) * D + h * DK;
    size_t obB = ((size_t)jc * N + rowB) * D + h * DK;
    Opart[obA + c16] = O0A[e];
    Opart[obA + 16 + c16] = O1A[e];
    Opart[obB + c16] = O0B[e];
    Opart[obB + 16 + c16] = O1B[e];
    if (c16 == 0) {
      lpart[((size_t)jc * N + rowA) * H + h] = lrowA[e];
      lpart[((size_t)jc * N + rowB) * H + h] = lrowB[e];
    }
  }
}

// ---- fused: combine -> out-proj -> +bo+res -> LN1 -> FFN1(+gelu) -> hb ----
// grid N/16 = 128 blocks x 512 thr (8 waves); block owns 16 complete rows.
// G1: wave w covers cols 32w..32w+31. FFN1: wave w covers cols 128w..128w+127.
__global__ __launch_bounds__(512) void k_opln1f(
    const float* __restrict__ Opart, const float* __restrict__ lpart,
    const unsigned short* __restrict__ wo, const float* __restrict__ bo,
    const float* __restrict__ g1, const float* __restrict__ be1,
    const unsigned short* __restrict__ w1, const float* __restrict__ b1,
    float* __restrict__ x, unsigned short* __restrict__ hb) {
  __shared__ __align__(16) unsigned short Ab[16 * AB_STR];
  __shared__ __align__(16) float Xr[16][260];
  __shared__ float linv[16][8];
  __shared__ float red1[8][16], red2[8][16], mu[16], rsg[16];
  const int tid = threadIdx.x;
  const int w = tid >> 6, lane = tid & 63, quad = lane >> 4, c16 = lane & 15;
  const int r0 = blockIdx.x * 16;

  if (tid < 128) {
    int r = tid >> 3, hh = tid & 7;
    float ls = 0.f;
#pragma unroll
    for (int c = 0; c < JC; ++c) ls += lpart[((size_t)c * N + r0 + r) * H + hh];
    linv[r][hh] = 1.f / ls;
  }
  for (int i = tid; i < 16 * 64; i += 512) {
    int r = i >> 6, c4 = (i & 63) * 4;
    *(float4*)&Xr[r][c4] = *(const float4*)&x[(size_t)(r0 + r) * D + c4];
  }
  __syncthreads();
  // combine -> Ab bf16 (thread: 8 cols of one row; head const per 8-chunk)
  {
    const int r = tid >> 5, c0 = (tid & 31) * 8;
    float o[8];
#pragma unroll
    for (int j = 0; j < 8; ++j) o[j] = 0.f;
#pragma unroll
    for (int c = 0; c < JC; ++c) {
      const float* p = &Opart[((size_t)c * N + r0 + r) * D + c0];
      float4 p0 = *(const float4*)p;
      float4 p1 = *(const float4*)(p + 4);
      o[0] += p0.x; o[1] += p0.y; o[2] += p0.z; o[3] += p0.w;
      o[4] += p1.x; o[5] += p1.y; o[6] += p1.z; o[7] += p1.w;
    }
    const float iv = linv[r][c0 >> 5];
#pragma unroll
    for (int j = 0; j < 8; j += 2)
      *(unsigned int*)&Ab[r * AB_STR + c0 + j] = cvt_pk_bf16(o[j] * iv, o[j + 1] * iv);
  }
  __syncthreads();

  // ---- G1: out-proj (8 waves x 32 cols) ----
  short8 af[8];
#pragma unroll
  for (int k = 0; k < 8; ++k)
    af[k] = *(const short8*)&Ab[c16 * AB_STR + k * 32 + quad * 8];
  floatx4 acc[2] = {{0.f, 0.f, 0.f, 0.f}, {0.f, 0.f, 0.f, 0.f}};
#pragma unroll
  for (int ntt = 0; ntt < 2; ++ntt) {
    const int col = w * 32 + ntt * 16 + c16;
    const unsigned short* B = wo + (size_t)col * D + quad * 8;
#pragma unroll
    for (int k = 0; k < 8; ++k) acc[ntt] = MFMA(af[k], *(const short8*)(B + k * 32), acc[ntt]);
  }
  float v[2][4];
#pragma unroll
  for (int e = 0; e < 4; ++e) {
    const int row = quad * 4 + e;
    float s = 0.f, q = 0.f;
#pragma unroll
    for (int ntt = 0; ntt < 2; ++ntt) {
      const int col = w * 32 + ntt * 16 + c16;
      float vv = acc[ntt][e] + bo[col] + Xr[row][col];
      v[ntt][e] = vv;
      s += vv; q += vv * vv;
    }
    s += __shfl_xor(s, 1); s += __shfl_xor(s, 2);
    s += __shfl_xor(s, 4); s += __shfl_xor(s, 8);
    q += __shfl_xor(q, 1); q += __shfl_xor(q, 2);
    q += __shfl_xor(q, 4); q += __shfl_xor(q, 8);
    if (c16 == 0) { red1[w][row] = s; red2[w][row] = q; }
  }
  __syncthreads();
  if (tid < 16) {
    float m = 0.f, q = 0.f;
#pragma unroll
    for (int ww = 0; ww < 8; ++ww) { m += red1[ww][tid]; q += red2[ww][tid]; }
    m *= (1.f / 256.f);
    q = q * (1.f / 256.f) - m * m;
    mu[tid] = m;
    rsg[tid] = rsqrtf(q + 1e-5f);
  }
  __syncthreads();
  // LN1 -> x (fp32) + Ab (bf16, overwrites combine values; all reads done)
#pragma unroll
  for (int e = 0; e < 4; ++e) {
    const int row = quad * 4 + e;
#pragma unroll
    for (int ntt = 0; ntt < 2; ++ntt) {
      const int col = w * 32 + ntt * 16 + c16;
      float o = (v[ntt][e] - mu[row]) * rsg[row] * g1[col] + be1[col];
      x[(size_t)(r0 + row) * D + col] = o;
      Ab[row * AB_STR + col] = f2bf(o);
    }
  }
  __syncthreads();

  // ---- FFN1: (8 waves x 128 cols = 1024) + b1 + gelu -> hb ----
#pragma unroll
  for (int k = 0; k < 8; ++k)
    af[k] = *(const short8*)&Ab[c16 * AB_STR + k * 32 + quad * 8];
#pragma unroll
  for (int tp = 0; tp < 8; ++tp) {
    const int col = w * 128 + tp * 16 + c16;
    const unsigned short* B = w1 + (size_t)col * D + quad * 8;
    floatx4 a0 = {0.f, 0.f, 0.f, 0.f};
#pragma unroll
    for (int k = 0; k < 8; ++k) a0 = MFMA(af[k], *(const short8*)(B + k * 32), a0);
#pragma unroll
    for (int e = 0; e < 4; ++e) {
      const int row = quad * 4 + e;
      float hv = a0[e] + b1[col];
      hv = 0.5f * hv * (1.0f + erff(hv * 0.70710678118654752f));
      hb[(size_t)(r0 + row) * DFF + col] = f2bf(hv);
    }
  }
}

// ---- fused: FFN2 -> +b2+res -> LN2 -> next-layer QKV (or pool partials) ---
// grid N/16 = 128 blocks x 512 thr (8 waves); block owns 16 complete rows.
__global__ __launch_bounds__(512) void k_ffn2lnq(
    const unsigned short* __restrict__ hb, const unsigned short* __restrict__ w2,
    const float* __restrict__ b2,
    const float* __restrict__ g2, const float* __restrict__ be2,
    float* __restrict__ x,
    const unsigned short* __restrict__ wqkvn,
    unsigned short* __restrict__ qb, unsigned short* __restrict__ kb,
    unsigned short* __restrict__ vtb,
    float* __restrict__ ppool) {
  __shared__ __align__(16) unsigned short Hs[16 * HS_STR];
  __shared__ __align__(16) unsigned short Ab[16 * AB_STR];
  __shared__ __align__(16) float Xr[16][260];
  __shared__ float red1[8][16], red2[8][16], mu[16], rsg[16];
  const int tid = threadIdx.x;
  const int w = tid >> 6, lane = tid & 63, quad = lane >> 4, c16 = lane & 15;
  const int r0 = blockIdx.x * 16;

  // stage Hs: 16 rows x 1024 bf16; 512 thr x 4 passes of 8-elt chunks.
  {
#pragma unroll
    for (int pass = 0; pass < 4; ++pass) {
      const int idx = pass * 512 + tid;
      const int r = idx >> 7, c = idx & 127;
      async16(&Hs[r * HS_STR + c * 8], hb + (size_t)(r0 + r) * DFF + c * 8);
    }
  }
  for (int i = tid; i < 16 * 64; i += 512) {
    int r = i >> 6, c4 = (i & 63) * 4;
    *(float4*)&Xr[r][c4] = *(const float4*)&x[(size_t)(r0 + r) * D + c4];
  }
  __syncthreads();

  floatx4 acc[2] = {{0.f, 0.f, 0.f, 0.f}, {0.f, 0.f, 0.f, 0.f}};
  const int col0 = w * 32 + c16, col1 = w * 32 + 16 + c16;
  {
    const unsigned short* B0 = w2 + (size_t)col0 * DFF + quad * 8;
    const unsigned short* B1 = w2 + (size_t)col1 * DFF + quad * 8;
    for (int k = 0; k < 32; ++k) {
      short8 a = *(const short8*)&Hs[c16 * HS_STR + k * 32 + quad * 8];
      acc[0] = MFMA(a, *(const short8*)(B0 + k * 32), acc[0]);
      acc[1] = MFMA(a, *(const short8*)(B1 + k * 32), acc[1]);
    }
  }

  float v[2][4];
#pragma unroll
  for (int e = 0; e < 4; ++e) {
    const int row = quad * 4 + e;
    float s = 0.f, q = 0.f;
#pragma unroll
    for (int ntt = 0; ntt < 2; ++ntt) {
      const int col = w * 32 + ntt * 16 + c16;
      float vv = acc[ntt][e] + b2[col] + Xr[row][col];
      v[ntt][e] = vv;
      s += vv; q += vv * vv;
    }
    s += __shfl_xor(s, 1); s += __shfl_xor(s, 2);
    s += __shfl_xor(s, 4); s += __shfl_xor(s, 8);
    q += __shfl_xor(q, 1); q += __shfl_xor(q, 2);
    q += __shfl_xor(q, 4); q += __shfl_xor(q, 8);
    if (c16 == 0) { red1[w][row] = s; red2[w][row] = q; }
  }
  __syncthreads();
  if (tid < 16) {
    float m = 0.f, q = 0.f;
#pragma unroll
    for (int ww = 0; ww < 8; ++ww) { m += red1[ww][tid]; q += red2[ww][tid]; }
    m *= (1.f / 256.f);
    q = q * (1.f / 256.f) - m * m;
    mu[tid] = m;
    rsg[tid] = rsqrtf(q + 1e-5f);
  }
  __syncthreads();
  float psum[2], pmax[2];
#pragma unroll
  for (int ntt = 0; ntt < 2; ++ntt) { psum[ntt] = 0.f; pmax[ntt] = -INFINITY; }
#pragma unroll
  for (int e = 0; e < 4; ++e) {
    const int row = quad * 4 + e;
#pragma unroll
    for (int ntt = 0; ntt < 2; ++ntt) {
      const int col = w * 32 + ntt * 16 + c16;
      float o = (v[ntt][e] - mu[row]) * rsg[row] * g2[col] + be2[col];
      x[(size_t)(r0 + row) * D + col] = o;
      Ab[row * AB_STR + col] = f2bf(o);
      psum[ntt] += o;
      pmax[ntt] = fmaxf(pmax[ntt], o);
    }
  }
  if (wqkvn) {
    __syncthreads();
    qkv_from_Ab8(Ab, wqkvn, qb, kb, vtb, r0, w, quad, c16);
  } else if (ppool) {
#pragma unroll
    for (int ntt = 0; ntt < 2; ++ntt) {
      psum[ntt] += __shfl_xor(psum[ntt], 16);
      psum[ntt] += __shfl_xor(psum[ntt], 32);
      pmax[ntt] = fmaxf(pmax[ntt], __shfl_xor(pmax[ntt], 16));
      pmax[ntt] = fmaxf(pmax[ntt], __shfl_xor(pmax[ntt], 32));
    }
    if (quad == 0) {
      float* pp = ppool + (size_t)blockIdx.x * 512;
#pragma unroll
      for (int ntt = 0; ntt < 2; ++ntt) {
        const int col = w * 32 + ntt * 16 + c16;
        pp[col] = psum[ntt];
        pp[256 + col] = pmax[ntt];
      }
    }
  }
}

// ---- pool phase 2: reduce 128 partials + project (WrT contiguous rows) ----
__global__ __launch_bounds__(256) void k_pool2(const float* __restrict__ part,
                                               const float* __restrict__ WrT,
                                               const float* __restrict__ br,
                                               float* __restrict__ out) {
  __shared__ float pooled[2 * D];
  int d = threadIdx.x;
  float sum = 0.f, mx = -INFINITY;
  for (int b = 0; b < 128; ++b) {
    sum += part[(size_t)b * 512 + d];
    mx = fmaxf(mx, part[(size_t)b * 512 + 256 + d]);
  }
  pooled[d] = sum * (1.0f / N);
  pooled[D + d] = mx;
  __syncthreads();
  float acc = br[d];
  const float* wrow = WrT + (size_t)d * 512;
#pragma unroll 8
  for (int k2 = 0; k2 < 512; k2 += 4) {
    float4 wv = *(const float4*)(wrow + k2);
    acc += pooled[k2] * wv.x + pooled[k2 + 1] * wv.y +
           pooled[k2 + 2] * wv.z + pooled[k2 + 3] * wv.w;
  }
  out[d] = acc;
}

extern "C" void kernel_launch(void* const* d_in, const int* in_sizes, int n_in,
                              void* d_out, int out_size, void* d_ws, size_t ws_size,
                              hipStream_t stream) {
  const int* node_types = (const int*)d_in[0];
  const int* eidx = (const int*)d_in[1];
  const float* node_emb = (const float*)d_in[2];
  const float* Wq = (const float*)d_in[3];
  const float* Wk = (const float*)d_in[4];
  const float* Wv = (const float*)d_in[5];
  const float* Wo = (const float*)d_in[6];
  const float* bo = (const float*)d_in[7];
  const float* eb = (const float*)d_in[8];
  const float* W1 = (const float*)d_in[9];
  const float* b1 = (const float*)d_in[10];
  const float* W2 = (const float*)d_in[11];
  const float* b2 = (const float*)d_in[12];
  const float* g1 = (const float*)d_in[13];
  const float* be1 = (const float*)d_in[14];
  const float* g2 = (const float*)d_in[15];
  const float* be2 = (const float*)d_in[16];
  const float* Wr = (const float*)d_in[17];
  const float* br = (const float*)d_in[18];
  float* out = (float*)d_out;

  // workspace layout (xb eliminated: all LN outputs stay in-LDS as bf16)
  float* x = (float*)d_ws;                       // N*D fp32
  float* Opart = x + (size_t)N * D;              // JC*N*D fp32
  float* lpart = Opart + (size_t)JC * N * D;     // JC*N*H
  float* ppool = lpart + (size_t)JC * N * H;     // 128*512
  float* WrT = ppool + 128 * 512;                // 256*512 fp32
  unsigned short* qb = (unsigned short*)(WrT + 256 * 512);
  unsigned short* kb = qb + (size_t)N * D;
  unsigned short* vtb = kb + (size_t)N * D;      // (D, N) head-major d
  unsigned short* hb = vtb + (size_t)N * D;      // N*DFF
  unsigned short* wqkvb = hb + (size_t)N * DFF;  // L x (768, 256)
  unsigned short* wob = wqkvb + (size_t)L * 768 * D;
  unsigned short* w1b = wob + (size_t)L * D * D;
  unsigned short* w2b = w1b + (size_t)L * DFF * D;
  unsigned int* e8 = (unsigned int*)(w2b + (size_t)L * D * DFF);  // N*N bytes

  k_setup<<<7296, 256, 0, stream>>>(eidx, e8, Wq, Wk, Wv, Wo, W1, W2, Wr,
                                    wqkvb, wob, w1b, w2b, WrT);
  k_embed_qkv<<<128, 512, 0, stream>>>(node_types, node_emb, wqkvb, x, qb, kb, vtb);

  for (int l = 0; l < L; ++l) {
    k_attn<<<dim3(N / 32, JC), 512, 0, stream>>>(qb, kb, vtb, e8,
                                                 eb + (size_t)l * NEDGE * H,
                                                 Opart, lpart);
    k_opln1f<<<N / 16, 512, 0, stream>>>(
        Opart, lpart, wob + (size_t)l * D * D, bo + (size_t)l * D,
        g1 + (size_t)l * D, be1 + (size_t)l * D,
        w1b + (size_t)l * DFF * D, b1 + (size_t)l * DFF, x, hb);
    k_ffn2lnq<<<N / 16, 512, 0, stream>>>(
        hb, w2b + (size_t)l * D * DFF, b2 + (size_t)l * D,
        g2 + (size_t)l * D, be2 + (size_t)l * D, x,
        (l < L - 1) ? wqkvb + (size_t)(l + 1) * 768 * D : nullptr,
        qb, kb, vtb,
        (l == L - 1) ? ppool : nullptr);
  }

  k_pool2<<<1, 256, 0, stream>>>(ppool, WrT, br, out);
}

// Round 12
// 409.976 us; speedup vs baseline: 1.0938x; 1.0938x over previous
//
#include <hip/hip_runtime.h>
#include <math.h>

#define N 2048
#define D 256
#define H 8
#define DK 32
#define L 4
#define DFF 1024
#define NEDGE 5
#define JC 8  // attention j-chunks (flash-decode split)

typedef short short8 __attribute__((ext_vector_type(8)));
typedef float floatx4 __attribute__((ext_vector_type(4)));

// Q pre-scale: 1/sqrt(DK) * log2(e)  (attention uses raw v_exp_f32 = exp2)
#define QSCALE 0.25503485657f
#define LOG2E 1.4426950408889634f

#define MFMA(a, b, c) __builtin_amdgcn_mfma_f32_16x16x32_bf16(a, b, c, 0, 0, 0)

#define AB_STR 280   // (280*2/4)%32 = 12-bank row stride -> 2-way alias (free)
#define PB_STR 72
#define HS_STR 1048  // same 12-bank residue as AB_STR

__device__ __forceinline__ unsigned short f2bf(float f) {
  unsigned int u = __float_as_uint(f);
  u += 0x7fffu + ((u >> 16) & 1u);
  return (unsigned short)(u >> 16);
}

__device__ __forceinline__ float exp2_hw(float x) {
  float r;
  asm("v_exp_f32 %0, %1" : "=v"(r) : "v"(x));
  return r;
}

__device__ __forceinline__ unsigned int cvt_pk_bf16(float lo, float hi) {
  unsigned int r;
  asm("v_cvt_pk_bf16_f32 %0, %1, %2" : "=v"(r) : "v"(lo), "v"(hi));
  return r;
}

__device__ __forceinline__ void async16(unsigned short* lds, const unsigned short* g) {
  __builtin_amdgcn_global_load_lds(
      (const __attribute__((address_space(1))) unsigned int*)g,
      (__attribute__((address_space(3))) unsigned int*)lds, 16, 0, 0);
}

// ---- setup: e8 pack + weight transposes + WrT fp32 ------------------------
__global__ __launch_bounds__(256) void k_setup(
    const int* __restrict__ eidx, unsigned int* __restrict__ e8,
    const float* __restrict__ Wq, const float* __restrict__ Wk,
    const float* __restrict__ Wv, const float* __restrict__ Wo,
    const float* __restrict__ W1, const float* __restrict__ W2,
    const float* __restrict__ Wr,
    unsigned short* __restrict__ wqkvb, unsigned short* __restrict__ wob,
    unsigned short* __restrict__ w1b, unsigned short* __restrict__ w2b,
    float* __restrict__ WrT) {
  __shared__ float t[32][33];
  const int blk = blockIdx.x;
  const int tid = threadIdx.x;
  if (blk < 4096) {
    int i = blk * 256 + tid;  // word i = cols 4i..4i+3 of row i/512
    int4 v = ((const int4*)eidx)[i];
    e8[i] = (unsigned int)(v.x & 0xff) | ((unsigned int)(v.y & 0xff) << 8) |
            ((unsigned int)(v.z & 0xff) << 16) | ((unsigned int)(v.w & 0xff) << 24);
    return;
  }
  const int tx = tid & 31, ty = tid >> 5;
  if (blk >= 7168) {  // Wr (512,256) fp32 -> WrT (256,512) fp32
    int b5 = blk - 7168, bx = b5 & 7, by = b5 >> 3;
#pragma unroll
    for (int i = 0; i < 32; i += 8)
      t[ty + i][tx] = Wr[(size_t)(by * 32 + ty + i) * D + bx * 32 + tx];
    __syncthreads();
#pragma unroll
    for (int i = 0; i < 32; i += 8)
      WrT[(size_t)(bx * 32 + ty + i) * 512 + by * 32 + tx] = t[tx][ty + i];
    return;
  }
  const float* s;
  unsigned short* d;
  int rowOff, K_, N_, bx, by;
  if (blk < 5120) {
    int b2 = blk - 4096, z = b2 >> 6, rem = b2 & 63;
    int which = z >> 2, l = z & 3;
    s = (which == 0 ? Wq : which == 1 ? Wk : which == 2 ? Wv : Wo) + (size_t)l * D * D;
    if (which < 3) { d = wqkvb + (size_t)l * 768 * D; rowOff = which * 256; }
    else           { d = wob + (size_t)l * D * D;     rowOff = 0; }
    K_ = D; N_ = D; bx = rem & 7; by = rem >> 3;
  } else if (blk < 6144) {
    int b3 = blk - 5120, l = b3 >> 8, rem = b3 & 255;
    s = W1 + (size_t)l * D * DFF; d = w1b + (size_t)l * DFF * D; rowOff = 0;
    K_ = D; N_ = DFF; bx = rem & 31; by = rem >> 5;
  } else {
    int b4 = blk - 6144, l = b4 >> 8, rem = b4 & 255;
    s = W2 + (size_t)l * DFF * D; d = w2b + (size_t)l * D * DFF; rowOff = 0;
    K_ = DFF; N_ = D; bx = rem & 7; by = rem >> 3;
  }
  int n0 = bx * 32, k0 = by * 32;
#pragma unroll
  for (int i = 0; i < 32; i += 8) t[ty + i][tx] = s[(size_t)(k0 + ty + i) * N_ + n0 + tx];
  __syncthreads();
#pragma unroll
  for (int i = 0; i < 32; i += 8)
    d[(size_t)(rowOff + n0 + ty + i) * K_ + k0 + tx] = f2bf(t[tx][ty + i]);
}

// ---- qkv tail for 8-wave/16-row blocks (embed kernel only) ----------------
__device__ __forceinline__ void qkv_from_Ab8(
    const unsigned short* Ab, const unsigned short* __restrict__ wqkv,
    unsigned short* __restrict__ qb, unsigned short* __restrict__ kb,
    unsigned short* __restrict__ vtb, int r0, int w, int quad, int c16) {
  short8 af[8];
#pragma unroll
  for (int k = 0; k < 8; ++k)
    af[k] = *(const short8*)&Ab[c16 * AB_STR + k * 32 + quad * 8];
#pragma unroll
  for (int tp = 0; tp < 3; ++tp) {
    const int cb0 = (w * 6 + tp * 2) * 16 + c16;
    const int cb1 = cb0 + 16;
    const unsigned short* B0 = wqkv + (size_t)cb0 * D + quad * 8;
    const unsigned short* B1 = wqkv + (size_t)cb1 * D + quad * 8;
    floatx4 a0 = {0.f, 0.f, 0.f, 0.f}, a1 = {0.f, 0.f, 0.f, 0.f};
#pragma unroll
    for (int k = 0; k < 8; ++k) {
      a0 = MFMA(af[k], *(const short8*)(B0 + k * 32), a0);
      a1 = MFMA(af[k], *(const short8*)(B1 + k * 32), a1);
    }
#pragma unroll
    for (int e = 0; e < 4; ++e) {
      const int grow = r0 + quad * 4 + e;
#pragma unroll
      for (int half = 0; half < 2; ++half) {
        int gc = half ? cb1 : cb0;
        float v = half ? a1[e] : a0[e];
        if (gc < 256)      qb[(size_t)grow * D + gc] = f2bf(v * QSCALE);
        else if (gc < 512) kb[(size_t)grow * D + (gc - 256)] = f2bf(v);
        else               vtb[(size_t)(gc - 512) * N + grow] = f2bf(v);
      }
    }
  }
}

// ---- embed + layer-0 QKV --------------------------------------------------
__global__ __launch_bounds__(512) void k_embed_qkv(
    const int* __restrict__ nt, const float* __restrict__ emb,
    const unsigned short* __restrict__ wqkv0, float* __restrict__ x,
    unsigned short* __restrict__ qb, unsigned short* __restrict__ kb,
    unsigned short* __restrict__ vtb) {
  __shared__ __align__(16) unsigned short Ab[16 * AB_STR];
  const int tid = threadIdx.x;
  const int w = tid >> 6, lane = tid & 63, quad = lane >> 4, c16 = lane & 15;
  const int r0 = blockIdx.x * 16;
  {
    const int r = tid >> 5, cb = (tid & 31) * 8;
    const int ty = nt[r0 + r];
    float4 a = *(const float4*)&emb[(size_t)ty * D + cb];
    float4 b = *(const float4*)&emb[(size_t)ty * D + cb + 4];
    *(float4*)&x[(size_t)(r0 + r) * D + cb] = a;
    *(float4*)&x[(size_t)(r0 + r) * D + cb + 4] = b;
    Ab[r * AB_STR + cb + 0] = f2bf(a.x); Ab[r * AB_STR + cb + 1] = f2bf(a.y);
    Ab[r * AB_STR + cb + 2] = f2bf(a.z); Ab[r * AB_STR + cb + 3] = f2bf(a.w);
    Ab[r * AB_STR + cb + 4] = f2bf(b.x); Ab[r * AB_STR + cb + 5] = f2bf(b.y);
    Ab[r * AB_STR + cb + 6] = f2bf(b.z); Ab[r * AB_STR + cb + 7] = f2bf(b.w);
  }
  __syncthreads();
  qkv_from_Ab8(Ab, wqkv0, qb, kb, vtb, r0, w, quad, c16);
}

// ---- MFMA flash attention: QBLK=32, JC=8, m=0, contiguous-P ---------------
__global__ __launch_bounds__(512) void k_attn(const unsigned short* __restrict__ qb,
                                              const unsigned short* __restrict__ kb,
                                              const unsigned short* __restrict__ vt,
                                              const unsigned int* __restrict__ e8,
                                              const float* __restrict__ eb,
                                              float* __restrict__ Opart,
                                              float* __restrict__ lpart) {
  __shared__ __align__(16) unsigned short Pb[H][32 * PB_STR];
  __shared__ float ebh[H][NEDGE];
  __shared__ unsigned int e8s[32][65];
  const int tid = threadIdx.x;
  const int h = tid >> 6;
  const int lane = tid & 63;
  const int quad = lane >> 4;
  const int c16 = lane & 15;
  const int r0 = blockIdx.x * 32;
  const int jc = blockIdx.y;

  if (tid < NEDGE * H) ebh[tid % H][tid / H] = eb[tid] * LOG2E;
  for (int i = tid; i < 32 * 64; i += 512) {
    int r = i >> 6, ww = i & 63;
    e8s[r][ww] = e8[(size_t)(r0 + r) * (N / 4) + jc * 64 + ww];
  }
  __syncthreads();

  short8 aqA = *(const short8*)&qb[(size_t)(r0 + c16) * D + h * DK + quad * 8];
  short8 aqB = *(const short8*)&qb[(size_t)(r0 + 16 + c16) * D + h * DK + quad * 8];

  float lrowA[4] = {0.f, 0.f, 0.f, 0.f};
  float lrowB[4] = {0.f, 0.f, 0.f, 0.f};
  floatx4 O0A = {0.f, 0.f, 0.f, 0.f}, O1A = {0.f, 0.f, 0.f, 0.f};
  floatx4 O0B = {0.f, 0.f, 0.f, 0.f}, O1B = {0.f, 0.f, 0.f, 0.f};

  for (int g = 0; g < (N / JC) / 64; ++g) {
    const int j0 = jc * (N / JC) + g * 64;
    short8 bk[4];
#pragma unroll
    for (int t = 0; t < 4; ++t)
      bk[t] = *(const short8*)&kb[(size_t)(j0 + c16 * 4 + t) * D + h * DK + quad * 8];
    {
      unsigned int wrd[4];
#pragma unroll
      for (int e = 0; e < 4; ++e) wrd[e] = e8s[quad * 4 + e][g * 16 + c16];
      floatx4 Sc[4];
#pragma unroll
      for (int t = 0; t < 4; ++t) {
        floatx4 cbv;
#pragma unroll
        for (int e = 0; e < 4; ++e) cbv[e] = ebh[h][(wrd[e] >> (8 * t)) & 0xff];
        Sc[t] = MFMA(aqA, bk[t], cbv);
      }
      float p[4][4];
#pragma unroll
      for (int e = 0; e < 4; ++e) {
#pragma unroll
        for (int t = 0; t < 4; ++t) p[t][e] = exp2_hw(Sc[t][e]);
        lrowA[e] += (p[0][e] + p[1][e]) + (p[2][e] + p[3][e]);
      }
#pragma unroll
      for (int e = 0; e < 4; ++e) {
        uint2 u;
        u.x = cvt_pk_bf16(p[0][e], p[1][e]);
        u.y = cvt_pk_bf16(p[2][e], p[3][e]);
        *(uint2*)&Pb[h][(quad * 4 + e) * PB_STR + c16 * 4] = u;
      }
    }
    {
      unsigned int wrd[4];
#pragma unroll
      for (int e = 0; e < 4; ++e) wrd[e] = e8s[16 + quad * 4 + e][g * 16 + c16];
      floatx4 Sc[4];
#pragma unroll
      for (int t = 0; t < 4; ++t) {
        floatx4 cbv;
#pragma unroll
        for (int e = 0; e < 4; ++e) cbv[e] = ebh[h][(wrd[e] >> (8 * t)) & 0xff];
        Sc[t] = MFMA(aqB, bk[t], cbv);
      }
      float p[4][4];
#pragma unroll
      for (int e = 0; e < 4; ++e) {
#pragma unroll
        for (int t = 0; t < 4; ++t) p[t][e] = exp2_hw(Sc[t][e]);
        lrowB[e] += (p[0][e] + p[1][e]) + (p[2][e] + p[3][e]);
      }
#pragma unroll
      for (int e = 0; e < 4; ++e) {
        uint2 u;
        u.x = cvt_pk_bf16(p[0][e], p[1][e]);
        u.y = cvt_pk_bf16(p[2][e], p[3][e]);
        *(uint2*)&Pb[h][(16 + quad * 4 + e) * PB_STR + c16 * 4] = u;
      }
    }
    asm volatile("" ::: "memory");
#pragma unroll
    for (int jj = 0; jj < 2; ++jj) {
      short8 apA = *(const short8*)&Pb[h][c16 * PB_STR + jj * 32 + quad * 8];
      short8 apB = *(const short8*)&Pb[h][(16 + c16) * PB_STR + jj * 32 + quad * 8];
      short8 bv0 = *(const short8*)&vt[(size_t)(h * DK + c16) * N + j0 + jj * 32 + quad * 8];
      short8 bv1 = *(const short8*)&vt[(size_t)(h * DK + 16 + c16) * N + j0 + jj * 32 + quad * 8];
      O0A = MFMA(apA, bv0, O0A); O1A = MFMA(apA, bv1, O1A);
      O0B = MFMA(apB, bv0, O0B); O1B = MFMA(apB, bv1, O1B);
    }
    asm volatile("" ::: "memory");
  }

#pragma unroll
  for (int e = 0; e < 4; ++e) {
    float va = lrowA[e], vb = lrowB[e];
    va += __shfl_xor(va, 1); va += __shfl_xor(va, 2);
    va += __shfl_xor(va, 4); va += __shfl_xor(va, 8);
    vb += __shfl_xor(vb, 1); vb += __shfl_xor(vb, 2);
    vb += __shfl_xor(vb, 4); vb += __shfl_xor(vb, 8);
    lrowA[e] = va; lrowB[e] = vb;
  }
#pragma unroll
  for (int e = 0; e < 4; ++e) {
    int rowA = r0 + quad * 4 + e, rowB = rowA + 16;
    size_t obA = ((size_t)jc * N + rowA) * D + h * DK;
    size_t obB = ((size_t)jc * N + rowB) * D + h * DK;
    Opart[obA + c16] = O0A[e];
    Opart[obA + 16 + c16] = O1A[e];
    Opart[obB + c16] = O0B[e];
    Opart[obB + 16 + c16] = O1B[e];
    if (c16 == 0) {
      lpart[((size_t)jc * N + rowA) * H + h] = lrowA[e];
      lpart[((size_t)jc * N + rowB) * H + h] = lrowB[e];
    }
  }
}

// ---- fused: attn-combine -> out-proj GEMM -> +bo +res -> LN1 -> x, xb -----
// grid N/16 = 128 blocks x 512 thr (8 waves). Block owns 16 COMPLETE rows;
// wave w covers cols 32w..32w+31 (2 n-tiles) -> 2 waves/SIMD latency hiding.
__global__ __launch_bounds__(512) void k_opln1(
    const float* __restrict__ Opart, const float* __restrict__ lpart,
    const unsigned short* __restrict__ wo, const float* __restrict__ bo,
    const float* __restrict__ g1, const float* __restrict__ be1,
    float* __restrict__ x, unsigned short* __restrict__ xb) {
  __shared__ __align__(16) unsigned short Ab[16 * AB_STR];
  __shared__ __align__(16) float Xr[16][260];
  __shared__ float linv[16][8];
  __shared__ float red1[8][16], red2[8][16], mu[16], rsg[16];
  const int tid = threadIdx.x;
  const int w = tid >> 6, lane = tid & 63, quad = lane >> 4, c16 = lane & 15;
  const int r0 = blockIdx.x * 16;

  if (tid < 128) {
    int r = tid >> 3, hh = tid & 7;
    float ls = 0.f;
#pragma unroll
    for (int c = 0; c < JC; ++c) ls += lpart[((size_t)c * N + r0 + r) * H + hh];
    linv[r][hh] = 1.f / ls;
  }
  for (int i = tid; i < 16 * 64; i += 512) {
    int r = i >> 6, c4 = (i & 63) * 4;
    *(float4*)&Xr[r][c4] = *(const float4*)&x[(size_t)(r0 + r) * D + c4];
  }
  __syncthreads();
  // combine -> Ab bf16 (thread: 8 cols of one row; head const per 8-chunk)
  {
    const int r = tid >> 5, c0 = (tid & 31) * 8;
    float o[8];
#pragma unroll
    for (int j = 0; j < 8; ++j) o[j] = 0.f;
#pragma unroll
    for (int c = 0; c < JC; ++c) {
      const float* p = &Opart[((size_t)c * N + r0 + r) * D + c0];
      float4 p0 = *(const float4*)p;
      float4 p1 = *(const float4*)(p + 4);
      o[0] += p0.x; o[1] += p0.y; o[2] += p0.z; o[3] += p0.w;
      o[4] += p1.x; o[5] += p1.y; o[6] += p1.z; o[7] += p1.w;
    }
    const float iv = linv[r][c0 >> 5];
#pragma unroll
    for (int j = 0; j < 8; j += 2)
      *(unsigned int*)&Ab[r * AB_STR + c0 + j] = cvt_pk_bf16(o[j] * iv, o[j + 1] * iv);
  }
  __syncthreads();

  short8 af[8];
#pragma unroll
  for (int k = 0; k < 8; ++k)
    af[k] = *(const short8*)&Ab[c16 * AB_STR + k * 32 + quad * 8];
  floatx4 acc[2] = {{0.f, 0.f, 0.f, 0.f}, {0.f, 0.f, 0.f, 0.f}};
#pragma unroll
  for (int ntt = 0; ntt < 2; ++ntt) {
    const int col = w * 32 + ntt * 16 + c16;
    const unsigned short* B = wo + (size_t)col * D + quad * 8;
#pragma unroll
    for (int k = 0; k < 8; ++k) acc[ntt] = MFMA(af[k], *(const short8*)(B + k * 32), acc[ntt]);
  }
  float v[2][4];
#pragma unroll
  for (int e = 0; e < 4; ++e) {
    const int row = quad * 4 + e;
    float s = 0.f, q = 0.f;
#pragma unroll
    for (int ntt = 0; ntt < 2; ++ntt) {
      const int col = w * 32 + ntt * 16 + c16;
      float vv = acc[ntt][e] + bo[col] + Xr[row][col];
      v[ntt][e] = vv;
      s += vv; q += vv * vv;
    }
    s += __shfl_xor(s, 1); s += __shfl_xor(s, 2);
    s += __shfl_xor(s, 4); s += __shfl_xor(s, 8);
    q += __shfl_xor(q, 1); q += __shfl_xor(q, 2);
    q += __shfl_xor(q, 4); q += __shfl_xor(q, 8);
    if (c16 == 0) { red1[w][row] = s; red2[w][row] = q; }
  }
  __syncthreads();
  if (tid < 16) {
    float m = 0.f, q = 0.f;
#pragma unroll
    for (int ww = 0; ww < 8; ++ww) { m += red1[ww][tid]; q += red2[ww][tid]; }
    m *= (1.f / 256.f);
    q = q * (1.f / 256.f) - m * m;
    mu[tid] = m;
    rsg[tid] = rsqrtf(q + 1e-5f);
  }
  __syncthreads();
#pragma unroll
  for (int e = 0; e < 4; ++e) {
    const int row = quad * 4 + e;
#pragma unroll
    for (int ntt = 0; ntt < 2; ++ntt) {
      const int col = w * 32 + ntt * 16 + c16;
      float o = (v[ntt][e] - mu[row]) * rsg[row] * g1[col] + be1[col];
      x[(size_t)(r0 + row) * D + col] = o;
      xb[(size_t)(r0 + row) * D + col] = f2bf(o);
    }
  }
}

// ---- bf16 MFMA GEMM (FFN1 only): C = A @ Bt^T +bias +gelu -> bf16 ---------
__global__ __launch_bounds__(256) void k_mm(const unsigned short* __restrict__ A,
                                            const unsigned short* __restrict__ Bt,
                                            int Nn, int Kfull, int Klen,
                                            const float* __restrict__ bias,
                                            int gelu,
                                            float* __restrict__ outf,
                                            unsigned short* __restrict__ outb) {
  __shared__ unsigned short As[64 * 32];
  __shared__ unsigned short Bs[64 * 32];
  int tid = threadIdx.x;
  int w = tid >> 6, lane = tid & 63, quad = lane >> 4, c16 = lane & 15;
  int bm = blockIdx.y * 64, bn = blockIdx.x * 64;
  int z = blockIdx.z;
  int kBase = z * Klen;
  int srow = w * 16 + (lane >> 2);
  int schk = (lane & 3) * 8;
  const unsigned short* gA = A + (size_t)(bm + srow) * Kfull + kBase + schk;
  const unsigned short* gB = Bt + (size_t)(bn + srow) * Kfull + kBase + schk;
  unsigned short* lA = &As[w * 512 + lane * 8];
  unsigned short* lB = &Bs[w * 512 + lane * 8];

  floatx4 acc[4] = {{0.f, 0.f, 0.f, 0.f}, {0.f, 0.f, 0.f, 0.f},
                    {0.f, 0.f, 0.f, 0.f}, {0.f, 0.f, 0.f, 0.f}};
  for (int k0 = 0; k0 < Klen; k0 += 32) {
    async16(lA, gA + k0);
    async16(lB, gB + k0);
    __syncthreads();
    short8 a = *(const short8*)&As[(w * 16 + c16) * 32 + quad * 8];
#pragma unroll
    for (int ntt = 0; ntt < 4; ++ntt) {
      short8 b = *(const short8*)&Bs[(ntt * 16 + c16) * 32 + quad * 8];
      acc[ntt] = MFMA(a, b, acc[ntt]);
    }
    __syncthreads();
  }
#pragma unroll
  for (int ntt = 0; ntt < 4; ++ntt) {
#pragma unroll
    for (int e = 0; e < 4; ++e) {
      int row = bm + w * 16 + quad * 4 + e;
      int col = bn + ntt * 16 + c16;
      float v = acc[ntt][e];
      if (z == 0) v += bias[col];
      if (gelu) v = 0.5f * v * (1.0f + erff(v * 0.70710678118654752f));
      if (outf) outf[(size_t)z * N * Nn + (size_t)row * Nn + col] = v;
      if (outb) outb[(size_t)row * Nn + col] = f2bf(v);
    }
  }
}

// ---- fused: FFN2 GEMM (complete rows, K=1024) -> +b2 +res -> LN2 ----------
// grid N/16 = 128 blocks x 512 thr (8 waves); wave w covers cols 32w..32w+31
// (2 n-tiles x 32 k-steps = 64 MFMA/wave) -> 2 waves/SIMD latency hiding.
__global__ __launch_bounds__(512) void k_ffn2ln(
    const unsigned short* __restrict__ hb, const unsigned short* __restrict__ w2,
    const float* __restrict__ b2,
    const float* __restrict__ g2, const float* __restrict__ be2,
    float* __restrict__ x, unsigned short* __restrict__ xb,
    float* __restrict__ ppool) {
  __shared__ __align__(16) unsigned short Hs[16 * HS_STR];
  __shared__ __align__(16) float Xr[16][260];
  __shared__ float red1[8][16], red2[8][16], mu[16], rsg[16];
  const int tid = threadIdx.x;
  const int w = tid >> 6, lane = tid & 63, quad = lane >> 4, c16 = lane & 15;
  const int r0 = blockIdx.x * 16;

  // stage Hs: 16 rows x 1024 bf16 = 2048 chunks of 8; 512 thr x 4 passes.
  {
#pragma unroll
    for (int pass = 0; pass < 4; ++pass) {
      const int idx = pass * 512 + tid;     // (r, chunk): r = idx>>7, c = idx&127
      const int r = idx >> 7, c = idx & 127;
      async16(&Hs[r * HS_STR + c * 8], hb + (size_t)(r0 + r) * DFF + c * 8);
    }
  }
  for (int i = tid; i < 16 * 64; i += 512) {
    int r = i >> 6, c4 = (i & 63) * 4;
    *(float4*)&Xr[r][c4] = *(const float4*)&x[(size_t)(r0 + r) * D + c4];
  }
  __syncthreads();

  floatx4 acc[2] = {{0.f, 0.f, 0.f, 0.f}, {0.f, 0.f, 0.f, 0.f}};
  const int col0 = w * 32 + c16, col1 = w * 32 + 16 + c16;
  {
    const unsigned short* B0 = w2 + (size_t)col0 * DFF + quad * 8;
    const unsigned short* B1 = w2 + (size_t)col1 * DFF + quad * 8;
    for (int k = 0; k < 32; ++k) {
      short8 a = *(const short8*)&Hs[c16 * HS_STR + k * 32 + quad * 8];
      acc[0] = MFMA(a, *(const short8*)(B0 + k * 32), acc[0]);
      acc[1] = MFMA(a, *(const short8*)(B1 + k * 32), acc[1]);
    }
  }

  float v[2][4];
#pragma unroll
  for (int e = 0; e < 4; ++e) {
    const int row = quad * 4 + e;
    float s = 0.f, q = 0.f;
#pragma unroll
    for (int ntt = 0; ntt < 2; ++ntt) {
      const int col = w * 32 + ntt * 16 + c16;
      float vv = acc[ntt][e] + b2[col] + Xr[row][col];
      v[ntt][e] = vv;
      s += vv; q += vv * vv;
    }
    s += __shfl_xor(s, 1); s += __shfl_xor(s, 2);
    s += __shfl_xor(s, 4); s += __shfl_xor(s, 8);
    q += __shfl_xor(q, 1); q += __shfl_xor(q, 2);
    q += __shfl_xor(q, 4); q += __shfl_xor(q, 8);
    if (c16 == 0) { red1[w][row] = s; red2[w][row] = q; }
  }
  __syncthreads();
  if (tid < 16) {
    float m = 0.f, q = 0.f;
#pragma unroll
    for (int ww = 0; ww < 8; ++ww) { m += red1[ww][tid]; q += red2[ww][tid]; }
    m *= (1.f / 256.f);
    q = q * (1.f / 256.f) - m * m;
    mu[tid] = m;
    rsg[tid] = rsqrtf(q + 1e-5f);
  }
  __syncthreads();
  float psum[2], pmax[2];
#pragma unroll
  for (int ntt = 0; ntt < 2; ++ntt) { psum[ntt] = 0.f; pmax[ntt] = -INFINITY; }
#pragma unroll
  for (int e = 0; e < 4; ++e) {
    const int row = quad * 4 + e;
#pragma unroll
    for (int ntt = 0; ntt < 2; ++ntt) {
      const int col = w * 32 + ntt * 16 + c16;
      float o = (v[ntt][e] - mu[row]) * rsg[row] * g2[col] + be2[col];
      x[(size_t)(r0 + row) * D + col] = o;
      xb[(size_t)(r0 + row) * D + col] = f2bf(o);
      psum[ntt] += o;
      pmax[ntt] = fmaxf(pmax[ntt], o);
    }
  }
  if (ppool) {
#pragma unroll
    for (int ntt = 0; ntt < 2; ++ntt) {
      psum[ntt] += __shfl_xor(psum[ntt], 16);
      psum[ntt] += __shfl_xor(psum[ntt], 32);
      pmax[ntt] = fmaxf(pmax[ntt], __shfl_xor(pmax[ntt], 16));
      pmax[ntt] = fmaxf(pmax[ntt], __shfl_xor(pmax[ntt], 32));
    }
    if (quad == 0) {
      float* pp = ppool + (size_t)blockIdx.x * 512;
#pragma unroll
      for (int ntt = 0; ntt < 2; ++ntt) {
        const int col = w * 32 + ntt * 16 + c16;
        pp[col] = psum[ntt];
        pp[256 + col] = pmax[ntt];
      }
    }
  }
}

// ---- fused QKV GEMM: Nn=768; writes qb (pre-scaled), kb, vt (D,N) bf16 ----
__global__ __launch_bounds__(256) void k_mm_qkv(const unsigned short* __restrict__ A,
                                                const unsigned short* __restrict__ Bt,
                                                unsigned short* __restrict__ qb,
                                                unsigned short* __restrict__ kb,
                                                unsigned short* __restrict__ vtb) {
  const int K = D;
  __shared__ unsigned short As[64 * 32];
  __shared__ unsigned short Bs[64 * 32];
  int tid = threadIdx.x;
  int w = tid >> 6, lane = tid & 63, quad = lane >> 4, c16 = lane & 15;
  int bm = blockIdx.y * 64, bn = blockIdx.x * 64;
  int srow = w * 16 + (lane >> 2);
  int schk = (lane & 3) * 8;
  const unsigned short* gA = A + (size_t)(bm + srow) * K + schk;
  const unsigned short* gB = Bt + (size_t)(bn + srow) * K + schk;
  unsigned short* lA = &As[w * 512 + lane * 8];
  unsigned short* lB = &Bs[w * 512 + lane * 8];

  floatx4 acc[4] = {{0.f, 0.f, 0.f, 0.f}, {0.f, 0.f, 0.f, 0.f},
                    {0.f, 0.f, 0.f, 0.f}, {0.f, 0.f, 0.f, 0.f}};
  for (int k0 = 0; k0 < K; k0 += 32) {
    async16(lA, gA + k0);
    async16(lB, gB + k0);
    __syncthreads();
    short8 a = *(const short8*)&As[(w * 16 + c16) * 32 + quad * 8];
#pragma unroll
    for (int ntt = 0; ntt < 4; ++ntt) {
      short8 b = *(const short8*)&Bs[(ntt * 16 + c16) * 32 + quad * 8];
      acc[ntt] = MFMA(a, b, acc[ntt]);
    }
    __syncthreads();
  }
#pragma unroll
  for (int ntt = 0; ntt < 4; ++ntt) {
#pragma unroll
    for (int e = 0; e < 4; ++e) {
      int row = bm + w * 16 + quad * 4 + e;
      int col = bn + ntt * 16 + c16;  // q:0-255, k:256-511, v:512-767
      float v = acc[ntt][e];
      if (col < 256) v *= QSCALE;
      unsigned short bv = f2bf(v);
      if (col < 512) {
        unsigned short* dst = (col < 256) ? qb : kb;
        dst[(size_t)row * D + (col & 255)] = bv;
      } else {
        vtb[(size_t)(col - 512) * N + row] = bv;
      }
    }
  }
}

// ---- pool phase 2: reduce 128 partials + project (WrT contiguous rows) ----
__global__ __launch_bounds__(256) void k_pool2(const float* __restrict__ part,
                                               const float* __restrict__ WrT,
                                               const float* __restrict__ br,
                                               float* __restrict__ out) {
  __shared__ float pooled[2 * D];
  int d = threadIdx.x;
  float sum = 0.f, mx = -INFINITY;
  for (int b = 0; b < 128; ++b) {
    sum += part[(size_t)b * 512 + d];
    mx = fmaxf(mx, part[(size_t)b * 512 + 256 + d]);
  }
  pooled[d] = sum * (1.0f / N);
  pooled[D + d] = mx;
  __syncthreads();
  float acc = br[d];
  const float* wrow = WrT + (size_t)d * 512;
#pragma unroll 8
  for (int k2 = 0; k2 < 512; k2 += 4) {
    float4 wv = *(const float4*)(wrow + k2);
    acc += pooled[k2] * wv.x + pooled[k2 + 1] * wv.y +
           pooled[k2 + 2] * wv.z + pooled[k2 + 3] * wv.w;
  }
  out[d] = acc;
}

extern "C" void kernel_launch(void* const* d_in, const int* in_sizes, int n_in,
                              void* d_out, int out_size, void* d_ws, size_t ws_size,
                              hipStream_t stream) {
  const int* node_types = (const int*)d_in[0];
  const int* eidx = (const int*)d_in[1];
  const float* node_emb = (const float*)d_in[2];
  const float* Wq = (const float*)d_in[3];
  const float* Wk = (const float*)d_in[4];
  const float* Wv = (const float*)d_in[5];
  const float* Wo = (const float*)d_in[6];
  const float* bo = (const float*)d_in[7];
  const float* eb = (const float*)d_in[8];
  const float* W1 = (const float*)d_in[9];
  const float* b1 = (const float*)d_in[10];
  const float* W2 = (const float*)d_in[11];
  const float* b2 = (const float*)d_in[12];
  const float* g1 = (const float*)d_in[13];
  const float* be1 = (const float*)d_in[14];
  const float* g2 = (const float*)d_in[15];
  const float* be2 = (const float*)d_in[16];
  const float* Wr = (const float*)d_in[17];
  const float* br = (const float*)d_in[18];
  float* out = (float*)d_out;

  // workspace layout
  float* x = (float*)d_ws;                       // N*D fp32
  float* Opart = x + (size_t)N * D;              // JC*N*D fp32
  float* lpart = Opart + (size_t)JC * N * D;     // JC*N*H
  float* ppool = lpart + (size_t)JC * N * H;     // 128*512
  float* WrT = ppool + 128 * 512;                // 256*512 fp32
  unsigned short* xb = (unsigned short*)(WrT + 256 * 512);
  unsigned short* qb = xb + (size_t)N * D;
  unsigned short* kb = qb + (size_t)N * D;
  unsigned short* vtb = kb + (size_t)N * D;      // (D, N) head-major d
  unsigned short* hb = vtb + (size_t)N * D;      // N*DFF
  unsigned short* wqkvb = hb + (size_t)N * DFF;  // L x (768, 256)
  unsigned short* wob = wqkvb + (size_t)L * 768 * D;
  unsigned short* w1b = wob + (size_t)L * D * D;
  unsigned short* w2b = w1b + (size_t)L * DFF * D;
  unsigned int* e8 = (unsigned int*)(w2b + (size_t)L * D * DFF);  // N*N bytes

  k_setup<<<7296, 256, 0, stream>>>(eidx, e8, Wq, Wk, Wv, Wo, W1, W2, Wr,
                                    wqkvb, wob, w1b, w2b, WrT);
  k_embed_qkv<<<128, 512, 0, stream>>>(node_types, node_emb, wqkvb, x, qb, kb, vtb);

  for (int l = 0; l < L; ++l) {
    k_attn<<<dim3(N / 32, JC), 512, 0, stream>>>(qb, kb, vtb, e8,
                                                 eb + (size_t)l * NEDGE * H,
                                                 Opart, lpart);
    k_opln1<<<N / 16, 512, 0, stream>>>(Opart, lpart,
                                        wob + (size_t)l * D * D, bo + (size_t)l * D,
                                        g1 + (size_t)l * D, be1 + (size_t)l * D, x, xb);
    k_mm<<<dim3(DFF / 64, N / 64, 1), 256, 0, stream>>>(
        xb, w1b + (size_t)l * DFF * D, DFF, D, D, b1 + (size_t)l * DFF, 1,
        (float*)nullptr, hb);
    k_ffn2ln<<<N / 16, 512, 0, stream>>>(
        hb, w2b + (size_t)l * D * DFF, b2 + (size_t)l * D,
        g2 + (size_t)l * D, be2 + (size_t)l * D, x, xb,
        (l == L - 1) ? ppool : nullptr);
    if (l < L - 1) {
      k_mm_qkv<<<dim3(768 / 64, N / 64), 256, 0, stream>>>(
          xb, wqkvb + (size_t)(l + 1) * 768 * D, qb, kb, vtb);
    }
  }

  k_pool2<<<1, 256, 0, stream>>>(ppool, WrT, br, out);
}

// Round 13
// 398.963 us; speedup vs baseline: 1.1240x; 1.0276x over previous
//
#include <hip/hip_runtime.h>
#include <math.h>

#define N 2048
#define D 256
#define H 8
#define DK 32
#define L 4
#define DFF 1024
#define NEDGE 5
#define JC 4  // attention j-chunks; QBLK=32 -> grid 256 = 1 block/CU

typedef short short8 __attribute__((ext_vector_type(8)));
typedef float floatx4 __attribute__((ext_vector_type(4)));

// Q pre-scale: 1/sqrt(DK) * log2(e)  (attention uses raw v_exp_f32 = exp2)
#define QSCALE 0.25503485657f
#define LOG2E 1.4426950408889634f

#define MFMA(a, b, c) __builtin_amdgcn_mfma_f32_16x16x32_bf16(a, b, c, 0, 0, 0)

#define AB_STR 280   // (280*2/4)%32 = 12-bank row stride -> 2-way alias (free)
#define PB_STR 72
#define HS_STR 1048  // same 12-bank residue as AB_STR

__device__ __forceinline__ unsigned short f2bf(float f) {
  unsigned int u = __float_as_uint(f);
  u += 0x7fffu + ((u >> 16) & 1u);
  return (unsigned short)(u >> 16);
}

__device__ __forceinline__ float exp2_hw(float x) {
  float r;
  asm("v_exp_f32 %0, %1" : "=v"(r) : "v"(x));
  return r;
}

__device__ __forceinline__ unsigned int cvt_pk_bf16(float lo, float hi) {
  unsigned int r;
  asm("v_cvt_pk_bf16_f32 %0, %1, %2" : "=v"(r) : "v"(lo), "v"(hi));
  return r;
}

__device__ __forceinline__ void async16(unsigned short* lds, const unsigned short* g) {
  __builtin_amdgcn_global_load_lds(
      (const __attribute__((address_space(1))) unsigned int*)g,
      (__attribute__((address_space(3))) unsigned int*)lds, 16, 0, 0);
}

// ---- setup: e8 pack + weight transposes + WrT fp32 ------------------------
__global__ __launch_bounds__(256) void k_setup(
    const int* __restrict__ eidx, unsigned int* __restrict__ e8,
    const float* __restrict__ Wq, const float* __restrict__ Wk,
    const float* __restrict__ Wv, const float* __restrict__ Wo,
    const float* __restrict__ W1, const float* __restrict__ W2,
    const float* __restrict__ Wr,
    unsigned short* __restrict__ wqkvb, unsigned short* __restrict__ wob,
    unsigned short* __restrict__ w1b, unsigned short* __restrict__ w2b,
    float* __restrict__ WrT) {
  __shared__ float t[32][33];
  const int blk = blockIdx.x;
  const int tid = threadIdx.x;
  if (blk < 4096) {
    int i = blk * 256 + tid;  // word i = cols 4i..4i+3 of row i/512
    int4 v = ((const int4*)eidx)[i];
    e8[i] = (unsigned int)(v.x & 0xff) | ((unsigned int)(v.y & 0xff) << 8) |
            ((unsigned int)(v.z & 0xff) << 16) | ((unsigned int)(v.w & 0xff) << 24);
    return;
  }
  const int tx = tid & 31, ty = tid >> 5;
  if (blk >= 7168) {  // Wr (512,256) fp32 -> WrT (256,512) fp32
    int b5 = blk - 7168, bx = b5 & 7, by = b5 >> 3;
#pragma unroll
    for (int i = 0; i < 32; i += 8)
      t[ty + i][tx] = Wr[(size_t)(by * 32 + ty + i) * D + bx * 32 + tx];
    __syncthreads();
#pragma unroll
    for (int i = 0; i < 32; i += 8)
      WrT[(size_t)(bx * 32 + ty + i) * 512 + by * 32 + tx] = t[tx][ty + i];
    return;
  }
  const float* s;
  unsigned short* d;
  int rowOff, K_, N_, bx, by;
  if (blk < 5120) {
    int b2 = blk - 4096, z = b2 >> 6, rem = b2 & 63;
    int which = z >> 2, l = z & 3;
    s = (which == 0 ? Wq : which == 1 ? Wk : which == 2 ? Wv : Wo) + (size_t)l * D * D;
    if (which < 3) { d = wqkvb + (size_t)l * 768 * D; rowOff = which * 256; }
    else           { d = wob + (size_t)l * D * D;     rowOff = 0; }
    K_ = D; N_ = D; bx = rem & 7; by = rem >> 3;
  } else if (blk < 6144) {
    int b3 = blk - 5120, l = b3 >> 8, rem = b3 & 255;
    s = W1 + (size_t)l * D * DFF; d = w1b + (size_t)l * DFF * D; rowOff = 0;
    K_ = D; N_ = DFF; bx = rem & 31; by = rem >> 5;
  } else {
    int b4 = blk - 6144, l = b4 >> 8, rem = b4 & 255;
    s = W2 + (size_t)l * DFF * D; d = w2b + (size_t)l * D * DFF; rowOff = 0;
    K_ = DFF; N_ = D; bx = rem & 7; by = rem >> 3;
  }
  int n0 = bx * 32, k0 = by * 32;
#pragma unroll
  for (int i = 0; i < 32; i += 8) t[ty + i][tx] = s[(size_t)(k0 + ty + i) * N_ + n0 + tx];
  __syncthreads();
#pragma unroll
  for (int i = 0; i < 32; i += 8)
    d[(size_t)(rowOff + n0 + ty + i) * K_ + k0 + tx] = f2bf(t[tx][ty + i]);
}

// ---- qkv tail for 8-wave/16-row blocks (embed kernel only) ----------------
__device__ __forceinline__ void qkv_from_Ab8(
    const unsigned short* Ab, const unsigned short* __restrict__ wqkv,
    unsigned short* __restrict__ qb, unsigned short* __restrict__ kb,
    unsigned short* __restrict__ vtb, int r0, int w, int quad, int c16) {
  short8 af[8];
#pragma unroll
  for (int k = 0; k < 8; ++k)
    af[k] = *(const short8*)&Ab[c16 * AB_STR + k * 32 + quad * 8];
#pragma unroll
  for (int tp = 0; tp < 3; ++tp) {
    const int cb0 = (w * 6 + tp * 2) * 16 + c16;
    const int cb1 = cb0 + 16;
    const unsigned short* B0 = wqkv + (size_t)cb0 * D + quad * 8;
    const unsigned short* B1 = wqkv + (size_t)cb1 * D + quad * 8;
    floatx4 a0 = {0.f, 0.f, 0.f, 0.f}, a1 = {0.f, 0.f, 0.f, 0.f};
#pragma unroll
    for (int k = 0; k < 8; ++k) {
      a0 = MFMA(af[k], *(const short8*)(B0 + k * 32), a0);
      a1 = MFMA(af[k], *(const short8*)(B1 + k * 32), a1);
    }
#pragma unroll
    for (int e = 0; e < 4; ++e) {
      const int grow = r0 + quad * 4 + e;
#pragma unroll
      for (int half = 0; half < 2; ++half) {
        int gc = half ? cb1 : cb0;
        float v = half ? a1[e] : a0[e];
        if (gc < 256)      qb[(size_t)grow * D + gc] = f2bf(v * QSCALE);
        else if (gc < 512) kb[(size_t)grow * D + (gc - 256)] = f2bf(v);
        else               vtb[(size_t)(gc - 512) * N + grow] = f2bf(v);
      }
    }
  }
}

// ---- embed + layer-0 QKV --------------------------------------------------
__global__ __launch_bounds__(512) void k_embed_qkv(
    const int* __restrict__ nt, const float* __restrict__ emb,
    const unsigned short* __restrict__ wqkv0, float* __restrict__ x,
    unsigned short* __restrict__ qb, unsigned short* __restrict__ kb,
    unsigned short* __restrict__ vtb) {
  __shared__ __align__(16) unsigned short Ab[16 * AB_STR];
  const int tid = threadIdx.x;
  const int w = tid >> 6, lane = tid & 63, quad = lane >> 4, c16 = lane & 15;
  const int r0 = blockIdx.x * 16;
  {
    const int r = tid >> 5, cb = (tid & 31) * 8;
    const int ty = nt[r0 + r];
    float4 a = *(const float4*)&emb[(size_t)ty * D + cb];
    float4 b = *(const float4*)&emb[(size_t)ty * D + cb + 4];
    *(float4*)&x[(size_t)(r0 + r) * D + cb] = a;
    *(float4*)&x[(size_t)(r0 + r) * D + cb + 4] = b;
    Ab[r * AB_STR + cb + 0] = f2bf(a.x); Ab[r * AB_STR + cb + 1] = f2bf(a.y);
    Ab[r * AB_STR + cb + 2] = f2bf(a.z); Ab[r * AB_STR + cb + 3] = f2bf(a.w);
    Ab[r * AB_STR + cb + 4] = f2bf(b.x); Ab[r * AB_STR + cb + 5] = f2bf(b.y);
    Ab[r * AB_STR + cb + 6] = f2bf(b.z); Ab[r * AB_STR + cb + 7] = f2bf(b.w);
  }
  __syncthreads();
  qkv_from_Ab8(Ab, wqkv0, qb, kb, vtb, r0, w, quad, c16);
}

// ---- MFMA flash attention: QBLK=32, JC=4, m=0, contiguous-P ---------------
// grid (N/32, JC) = (64, 4) = 256 blocks (1/CU); block 512 (8 waves);
// wave h = head h, 32 Q-rows (two 16-row groups sharing K frags), 512 j-cols.
__global__ __launch_bounds__(512) void k_attn(const unsigned short* __restrict__ qb,
                                              const unsigned short* __restrict__ kb,
                                              const unsigned short* __restrict__ vt,
                                              const unsigned int* __restrict__ e8,
                                              const float* __restrict__ eb,
                                              float* __restrict__ Opart,
                                              float* __restrict__ lpart) {
  __shared__ __align__(16) unsigned short Pb[H][32 * PB_STR];
  __shared__ float ebh[H][NEDGE];
  __shared__ unsigned int e8s[32][129];
  const int tid = threadIdx.x;
  const int h = tid >> 6;
  const int lane = tid & 63;
  const int quad = lane >> 4;
  const int c16 = lane & 15;
  const int r0 = blockIdx.x * 32;
  const int jc = blockIdx.y;

  if (tid < NEDGE * H) ebh[tid % H][tid / H] = eb[tid] * LOG2E;
  for (int i = tid; i < 32 * 128; i += 512) {
    int r = i >> 7, ww = i & 127;
    e8s[r][ww] = e8[(size_t)(r0 + r) * (N / 4) + jc * 128 + ww];
  }
  __syncthreads();

  short8 aqA = *(const short8*)&qb[(size_t)(r0 + c16) * D + h * DK + quad * 8];
  short8 aqB = *(const short8*)&qb[(size_t)(r0 + 16 + c16) * D + h * DK + quad * 8];

  float lrowA[4] = {0.f, 0.f, 0.f, 0.f};
  float lrowB[4] = {0.f, 0.f, 0.f, 0.f};
  floatx4 O0A = {0.f, 0.f, 0.f, 0.f}, O1A = {0.f, 0.f, 0.f, 0.f};
  floatx4 O0B = {0.f, 0.f, 0.f, 0.f}, O1B = {0.f, 0.f, 0.f, 0.f};

  for (int g = 0; g < (N / JC) / 64; ++g) {
    const int j0 = jc * (N / JC) + g * 64;
    short8 bk[4];
#pragma unroll
    for (int t = 0; t < 4; ++t)
      bk[t] = *(const short8*)&kb[(size_t)(j0 + c16 * 4 + t) * D + h * DK + quad * 8];
    {
      unsigned int wrd[4];
#pragma unroll
      for (int e = 0; e < 4; ++e) wrd[e] = e8s[quad * 4 + e][g * 16 + c16];
      floatx4 Sc[4];
#pragma unroll
      for (int t = 0; t < 4; ++t) {
        floatx4 cbv;
#pragma unroll
        for (int e = 0; e < 4; ++e) cbv[e] = ebh[h][(wrd[e] >> (8 * t)) & 0xff];
        Sc[t] = MFMA(aqA, bk[t], cbv);
      }
      float p[4][4];
#pragma unroll
      for (int e = 0; e < 4; ++e) {
#pragma unroll
        for (int t = 0; t < 4; ++t) p[t][e] = exp2_hw(Sc[t][e]);
        lrowA[e] += (p[0][e] + p[1][e]) + (p[2][e] + p[3][e]);
      }
#pragma unroll
      for (int e = 0; e < 4; ++e) {
        uint2 u;
        u.x = cvt_pk_bf16(p[0][e], p[1][e]);
        u.y = cvt_pk_bf16(p[2][e], p[3][e]);
        *(uint2*)&Pb[h][(quad * 4 + e) * PB_STR + c16 * 4] = u;
      }
    }
    {
      unsigned int wrd[4];
#pragma unroll
      for (int e = 0; e < 4; ++e) wrd[e] = e8s[16 + quad * 4 + e][g * 16 + c16];
      floatx4 Sc[4];
#pragma unroll
      for (int t = 0; t < 4; ++t) {
        floatx4 cbv;
#pragma unroll
        for (int e = 0; e < 4; ++e) cbv[e] = ebh[h][(wrd[e] >> (8 * t)) & 0xff];
        Sc[t] = MFMA(aqB, bk[t], cbv);
      }
      float p[4][4];
#pragma unroll
      for (int e = 0; e < 4; ++e) {
#pragma unroll
        for (int t = 0; t < 4; ++t) p[t][e] = exp2_hw(Sc[t][e]);
        lrowB[e] += (p[0][e] + p[1][e]) + (p[2][e] + p[3][e]);
      }
#pragma unroll
      for (int e = 0; e < 4; ++e) {
        uint2 u;
        u.x = cvt_pk_bf16(p[0][e], p[1][e]);
        u.y = cvt_pk_bf16(p[2][e], p[3][e]);
        *(uint2*)&Pb[h][(16 + quad * 4 + e) * PB_STR + c16 * 4] = u;
      }
    }
    asm volatile("" ::: "memory");
#pragma unroll
    for (int jj = 0; jj < 2; ++jj) {
      short8 apA = *(const short8*)&Pb[h][c16 * PB_STR + jj * 32 + quad * 8];
      short8 apB = *(const short8*)&Pb[h][(16 + c16) * PB_STR + jj * 32 + quad * 8];
      short8 bv0 = *(const short8*)&vt[(size_t)(h * DK + c16) * N + j0 + jj * 32 + quad * 8];
      short8 bv1 = *(const short8*)&vt[(size_t)(h * DK + 16 + c16) * N + j0 + jj * 32 + quad * 8];
      O0A = MFMA(apA, bv0, O0A); O1A = MFMA(apA, bv1, O1A);
      O0B = MFMA(apB, bv0, O0B); O1B = MFMA(apB, bv1, O1B);
    }
    asm volatile("" ::: "memory");
  }

#pragma unroll
  for (int e = 0; e < 4; ++e) {
    float va = lrowA[e], vb = lrowB[e];
    va += __shfl_xor(va, 1); va += __shfl_xor(va, 2);
    va += __shfl_xor(va, 4); va += __shfl_xor(va, 8);
    vb += __shfl_xor(vb, 1); vb += __shfl_xor(vb, 2);
    vb += __shfl_xor(vb, 4); vb += __shfl_xor(vb, 8);
    lrowA[e] = va; lrowB[e] = vb;
  }
#pragma unroll
  for (int e = 0; e < 4; ++e) {
    int rowA = r0 + quad * 4 + e, rowB = rowA + 16;
    size_t obA = ((size_t)jc * N + rowA) * D + h * DK;
    size_t obB = ((size_t)jc * N + rowB) * D + h * DK;
    Opart[obA + c16] = O0A[e];
    Opart[obA + 16 + c16] = O1A[e];
    Opart[obB + c16] = O0B[e];
    Opart[obB + 16 + c16] = O1B[e];
    if (c16 == 0) {
      lpart[((size_t)jc * N + rowA) * H + h] = lrowA[e];
      lpart[((size_t)jc * N + rowB) * H + h] = lrowB[e];
    }
  }
}

// ---- fused: attn-combine -> out-proj GEMM -> +bo +res -> LN1 -> x, xb -----
// grid N/16 = 128 blocks x 512 thr (8 waves). Block owns 16 COMPLETE rows;
// wave w covers cols 32w..32w+31 (2 n-tiles) -> 2 waves/SIMD latency hiding.
__global__ __launch_bounds__(512) void k_opln1(
    const float* __restrict__ Opart, const float* __restrict__ lpart,
    const unsigned short* __restrict__ wo, const float* __restrict__ bo,
    const float* __restrict__ g1, const float* __restrict__ be1,
    float* __restrict__ x, unsigned short* __restrict__ xb) {
  __shared__ __align__(16) unsigned short Ab[16 * AB_STR];
  __shared__ __align__(16) float Xr[16][260];
  __shared__ float linv[16][8];
  __shared__ float red1[8][16], red2[8][16], mu[16], rsg[16];
  const int tid = threadIdx.x;
  const int w = tid >> 6, lane = tid & 63, quad = lane >> 4, c16 = lane & 15;
  const int r0 = blockIdx.x * 16;

  if (tid < 128) {
    int r = tid >> 3, hh = tid & 7;
    float ls = 0.f;
#pragma unroll
    for (int c = 0; c < JC; ++c) ls += lpart[((size_t)c * N + r0 + r) * H + hh];
    linv[r][hh] = 1.f / ls;
  }
  for (int i = tid; i < 16 * 64; i += 512) {
    int r = i >> 6, c4 = (i & 63) * 4;
    *(float4*)&Xr[r][c4] = *(const float4*)&x[(size_t)(r0 + r) * D + c4];
  }
  __syncthreads();
  // combine -> Ab bf16 (thread: 8 cols of one row; head const per 8-chunk)
  {
    const int r = tid >> 5, c0 = (tid & 31) * 8;
    float o[8];
#pragma unroll
    for (int j = 0; j < 8; ++j) o[j] = 0.f;
#pragma unroll
    for (int c = 0; c < JC; ++c) {
      const float* p = &Opart[((size_t)c * N + r0 + r) * D + c0];
      float4 p0 = *(const float4*)p;
      float4 p1 = *(const float4*)(p + 4);
      o[0] += p0.x; o[1] += p0.y; o[2] += p0.z; o[3] += p0.w;
      o[4] += p1.x; o[5] += p1.y; o[6] += p1.z; o[7] += p1.w;
    }
    const float iv = linv[r][c0 >> 5];
#pragma unroll
    for (int j = 0; j < 8; j += 2)
      *(unsigned int*)&Ab[r * AB_STR + c0 + j] = cvt_pk_bf16(o[j] * iv, o[j + 1] * iv);
  }
  __syncthreads();

  short8 af[8];
#pragma unroll
  for (int k = 0; k < 8; ++k)
    af[k] = *(const short8*)&Ab[c16 * AB_STR + k * 32 + quad * 8];
  floatx4 acc[2] = {{0.f, 0.f, 0.f, 0.f}, {0.f, 0.f, 0.f, 0.f}};
#pragma unroll
  for (int ntt = 0; ntt < 2; ++ntt) {
    const int col = w * 32 + ntt * 16 + c16;
    const unsigned short* B = wo + (size_t)col * D + quad * 8;
#pragma unroll
    for (int k = 0; k < 8; ++k) acc[ntt] = MFMA(af[k], *(const short8*)(B + k * 32), acc[ntt]);
  }
  float v[2][4];
#pragma unroll
  for (int e = 0; e < 4; ++e) {
    const int row = quad * 4 + e;
    float s = 0.f, q = 0.f;
#pragma unroll
    for (int ntt = 0; ntt < 2; ++ntt) {
      const int col = w * 32 + ntt * 16 + c16;
      float vv = acc[ntt][e] + bo[col] + Xr[row][col];
      v[ntt][e] = vv;
      s += vv; q += vv * vv;
    }
    s += __shfl_xor(s, 1); s += __shfl_xor(s, 2);
    s += __shfl_xor(s, 4); s += __shfl_xor(s, 8);
    q += __shfl_xor(q, 1); q += __shfl_xor(q, 2);
    q += __shfl_xor(q, 4); q += __shfl_xor(q, 8);
    if (c16 == 0) { red1[w][row] = s; red2[w][row] = q; }
  }
  __syncthreads();
  if (tid < 16) {
    float m = 0.f, q = 0.f;
#pragma unroll
    for (int ww = 0; ww < 8; ++ww) { m += red1[ww][tid]; q += red2[ww][tid]; }
    m *= (1.f / 256.f);
    q = q * (1.f / 256.f) - m * m;
    mu[tid] = m;
    rsg[tid] = rsqrtf(q + 1e-5f);
  }
  __syncthreads();
#pragma unroll
  for (int e = 0; e < 4; ++e) {
    const int row = quad * 4 + e;
#pragma unroll
    for (int ntt = 0; ntt < 2; ++ntt) {
      const int col = w * 32 + ntt * 16 + c16;
      float o = (v[ntt][e] - mu[row]) * rsg[row] * g1[col] + be1[col];
      x[(size_t)(r0 + row) * D + col] = o;
      xb[(size_t)(r0 + row) * D + col] = f2bf(o);
    }
  }
}

// ---- bf16 MFMA GEMM (FFN1 only): C = A @ Bt^T +bias +gelu -> bf16 ---------
__global__ __launch_bounds__(256) void k_mm(const unsigned short* __restrict__ A,
                                            const unsigned short* __restrict__ Bt,
                                            int Nn, int Kfull, int Klen,
                                            const float* __restrict__ bias,
                                            int gelu,
                                            float* __restrict__ outf,
                                            unsigned short* __restrict__ outb) {
  __shared__ unsigned short As[64 * 32];
  __shared__ unsigned short Bs[64 * 32];
  int tid = threadIdx.x;
  int w = tid >> 6, lane = tid & 63, quad = lane >> 4, c16 = lane & 15;
  int bm = blockIdx.y * 64, bn = blockIdx.x * 64;
  int z = blockIdx.z;
  int kBase = z * Klen;
  int srow = w * 16 + (lane >> 2);
  int schk = (lane & 3) * 8;
  const unsigned short* gA = A + (size_t)(bm + srow) * Kfull + kBase + schk;
  const unsigned short* gB = Bt + (size_t)(bn + srow) * Kfull + kBase + schk;
  unsigned short* lA = &As[w * 512 + lane * 8];
  unsigned short* lB = &Bs[w * 512 + lane * 8];

  floatx4 acc[4] = {{0.f, 0.f, 0.f, 0.f}, {0.f, 0.f, 0.f, 0.f},
                    {0.f, 0.f, 0.f, 0.f}, {0.f, 0.f, 0.f, 0.f}};
  for (int k0 = 0; k0 < Klen; k0 += 32) {
    async16(lA, gA + k0);
    async16(lB, gB + k0);
    __syncthreads();
    short8 a = *(const short8*)&As[(w * 16 + c16) * 32 + quad * 8];
#pragma unroll
    for (int ntt = 0; ntt < 4; ++ntt) {
      short8 b = *(const short8*)&Bs[(ntt * 16 + c16) * 32 + quad * 8];
      acc[ntt] = MFMA(a, b, acc[ntt]);
    }
    __syncthreads();
  }
#pragma unroll
  for (int ntt = 0; ntt < 4; ++ntt) {
#pragma unroll
    for (int e = 0; e < 4; ++e) {
      int row = bm + w * 16 + quad * 4 + e;
      int col = bn + ntt * 16 + c16;
      float v = acc[ntt][e];
      if (z == 0) v += bias[col];
      if (gelu) v = 0.5f * v * (1.0f + erff(v * 0.70710678118654752f));
      if (outf) outf[(size_t)z * N * Nn + (size_t)row * Nn + col] = v;
      if (outb) outb[(size_t)row * Nn + col] = f2bf(v);
    }
  }
}

// ---- fused: FFN2 GEMM (complete rows, K=1024) -> +b2 +res -> LN2 ----------
// grid N/16 = 128 blocks x 512 thr (8 waves); wave w covers cols 32w..32w+31
// (2 n-tiles x 32 k-steps = 64 MFMA/wave) -> 2 waves/SIMD latency hiding.
__global__ __launch_bounds__(512) void k_ffn2ln(
    const unsigned short* __restrict__ hb, const unsigned short* __restrict__ w2,
    const float* __restrict__ b2,
    const float* __restrict__ g2, const float* __restrict__ be2,
    float* __restrict__ x, unsigned short* __restrict__ xb,
    float* __restrict__ ppool) {
  __shared__ __align__(16) unsigned short Hs[16 * HS_STR];
  __shared__ __align__(16) float Xr[16][260];
  __shared__ float red1[8][16], red2[8][16], mu[16], rsg[16];
  const int tid = threadIdx.x;
  const int w = tid >> 6, lane = tid & 63, quad = lane >> 4, c16 = lane & 15;
  const int r0 = blockIdx.x * 16;

  // stage Hs: 16 rows x 1024 bf16 = 2048 chunks of 8; 512 thr x 4 passes.
  {
#pragma unroll
    for (int pass = 0; pass < 4; ++pass) {
      const int idx = pass * 512 + tid;     // (r, chunk): r = idx>>7, c = idx&127
      const int r = idx >> 7, c = idx & 127;
      async16(&Hs[r * HS_STR + c * 8], hb + (size_t)(r0 + r) * DFF + c * 8);
    }
  }
  for (int i = tid; i < 16 * 64; i += 512) {
    int r = i >> 6, c4 = (i & 63) * 4;
    *(float4*)&Xr[r][c4] = *(const float4*)&x[(size_t)(r0 + r) * D + c4];
  }
  __syncthreads();

  floatx4 acc[2] = {{0.f, 0.f, 0.f, 0.f}, {0.f, 0.f, 0.f, 0.f}};
  const int col0 = w * 32 + c16, col1 = w * 32 + 16 + c16;
  {
    const unsigned short* B0 = w2 + (size_t)col0 * DFF + quad * 8;
    const unsigned short* B1 = w2 + (size_t)col1 * DFF + quad * 8;
    for (int k = 0; k < 32; ++k) {
      short8 a = *(const short8*)&Hs[c16 * HS_STR + k * 32 + quad * 8];
      acc[0] = MFMA(a, *(const short8*)(B0 + k * 32), acc[0]);
      acc[1] = MFMA(a, *(const short8*)(B1 + k * 32), acc[1]);
    }
  }

  float v[2][4];
#pragma unroll
  for (int e = 0; e < 4; ++e) {
    const int row = quad * 4 + e;
    float s = 0.f, q = 0.f;
#pragma unroll
    for (int ntt = 0; ntt < 2; ++ntt) {
      const int col = w * 32 + ntt * 16 + c16;
      float vv = acc[ntt][e] + b2[col] + Xr[row][col];
      v[ntt][e] = vv;
      s += vv; q += vv * vv;
    }
    s += __shfl_xor(s, 1); s += __shfl_xor(s, 2);
    s += __shfl_xor(s, 4); s += __shfl_xor(s, 8);
    q += __shfl_xor(q, 1); q += __shfl_xor(q, 2);
    q += __shfl_xor(q, 4); q += __shfl_xor(q, 8);
    if (c16 == 0) { red1[w][row] = s; red2[w][row] = q; }
  }
  __syncthreads();
  if (tid < 16) {
    float m = 0.f, q = 0.f;
#pragma unroll
    for (int ww = 0; ww < 8; ++ww) { m += red1[ww][tid]; q += red2[ww][tid]; }
    m *= (1.f / 256.f);
    q = q * (1.f / 256.f) - m * m;
    mu[tid] = m;
    rsg[tid] = rsqrtf(q + 1e-5f);
  }
  __syncthreads();
  float psum[2], pmax[2];
#pragma unroll
  for (int ntt = 0; ntt < 2; ++ntt) { psum[ntt] = 0.f; pmax[ntt] = -INFINITY; }
#pragma unroll
  for (int e = 0; e < 4; ++e) {
    const int row = quad * 4 + e;
#pragma unroll
    for (int ntt = 0; ntt < 2; ++ntt) {
      const int col = w * 32 + ntt * 16 + c16;
      float o = (v[ntt][e] - mu[row]) * rsg[row] * g2[col] + be2[col];
      x[(size_t)(r0 + row) * D + col] = o;
      xb[(size_t)(r0 + row) * D + col] = f2bf(o);
      psum[ntt] += o;
      pmax[ntt] = fmaxf(pmax[ntt], o);
    }
  }
  if (ppool) {
#pragma unroll
    for (int ntt = 0; ntt < 2; ++ntt) {
      psum[ntt] += __shfl_xor(psum[ntt], 16);
      psum[ntt] += __shfl_xor(psum[ntt], 32);
      pmax[ntt] = fmaxf(pmax[ntt], __shfl_xor(pmax[ntt], 16));
      pmax[ntt] = fmaxf(pmax[ntt], __shfl_xor(pmax[ntt], 32));
    }
    if (quad == 0) {
      float* pp = ppool + (size_t)blockIdx.x * 512;
#pragma unroll
      for (int ntt = 0; ntt < 2; ++ntt) {
        const int col = w * 32 + ntt * 16 + c16;
        pp[col] = psum[ntt];
        pp[256 + col] = pmax[ntt];
      }
    }
  }
}

// ---- fused QKV GEMM: Nn=768; writes qb (pre-scaled), kb, vt (D,N) bf16 ----
__global__ __launch_bounds__(256) void k_mm_qkv(const unsigned short* __restrict__ A,
                                                const unsigned short* __restrict__ Bt,
                                                unsigned short* __restrict__ qb,
                                                unsigned short* __restrict__ kb,
                                                unsigned short* __restrict__ vtb) {
  const int K = D;
  __shared__ unsigned short As[64 * 32];
  __shared__ unsigned short Bs[64 * 32];
  int tid = threadIdx.x;
  int w = tid >> 6, lane = tid & 63, quad = lane >> 4, c16 = lane & 15;
  int bm = blockIdx.y * 64, bn = blockIdx.x * 64;
  int srow = w * 16 + (lane >> 2);
  int schk = (lane & 3) * 8;
  const unsigned short* gA = A + (size_t)(bm + srow) * K + schk;
  const unsigned short* gB = Bt + (size_t)(bn + srow) * K + schk;
  unsigned short* lA = &As[w * 512 + lane * 8];
  unsigned short* lB = &Bs[w * 512 + lane * 8];

  floatx4 acc[4] = {{0.f, 0.f, 0.f, 0.f}, {0.f, 0.f, 0.f, 0.f},
                    {0.f, 0.f, 0.f, 0.f}, {0.f, 0.f, 0.f, 0.f}};
  for (int k0 = 0; k0 < K; k0 += 32) {
    async16(lA, gA + k0);
    async16(lB, gB + k0);
    __syncthreads();
    short8 a = *(const short8*)&As[(w * 16 + c16) * 32 + quad * 8];
#pragma unroll
    for (int ntt = 0; ntt < 4; ++ntt) {
      short8 b = *(const short8*)&Bs[(ntt * 16 + c16) * 32 + quad * 8];
      acc[ntt] = MFMA(a, b, acc[ntt]);
    }
    __syncthreads();
  }
#pragma unroll
  for (int ntt = 0; ntt < 4; ++ntt) {
#pragma unroll
    for (int e = 0; e < 4; ++e) {
      int row = bm + w * 16 + quad * 4 + e;
      int col = bn + ntt * 16 + c16;  // q:0-255, k:256-511, v:512-767
      float v = acc[ntt][e];
      if (col < 256) v *= QSCALE;
      unsigned short bv = f2bf(v);
      if (col < 512) {
        unsigned short* dst = (col < 256) ? qb : kb;
        dst[(size_t)row * D + (col & 255)] = bv;
      } else {
        vtb[(size_t)(col - 512) * N + row] = bv;
      }
    }
  }
}

// ---- pool phase 2: reduce 128 partials + project (WrT contiguous rows) ----
__global__ __launch_bounds__(256) void k_pool2(const float* __restrict__ part,
                                               const float* __restrict__ WrT,
                                               const float* __restrict__ br,
                                               float* __restrict__ out) {
  __shared__ float pooled[2 * D];
  int d = threadIdx.x;
  float sum = 0.f, mx = -INFINITY;
  for (int b = 0; b < 128; ++b) {
    sum += part[(size_t)b * 512 + d];
    mx = fmaxf(mx, part[(size_t)b * 512 + 256 + d]);
  }
  pooled[d] = sum * (1.0f / N);
  pooled[D + d] = mx;
  __syncthreads();
  float acc = br[d];
  const float* wrow = WrT + (size_t)d * 512;
#pragma unroll 8
  for (int k2 = 0; k2 < 512; k2 += 4) {
    float4 wv = *(const float4*)(wrow + k2);
    acc += pooled[k2] * wv.x + pooled[k2 + 1] * wv.y +
           pooled[k2 + 2] * wv.z + pooled[k2 + 3] * wv.w;
  }
  out[d] = acc;
}

extern "C" void kernel_launch(void* const* d_in, const int* in_sizes, int n_in,
                              void* d_out, int out_size, void* d_ws, size_t ws_size,
                              hipStream_t stream) {
  const int* node_types = (const int*)d_in[0];
  const int* eidx = (const int*)d_in[1];
  const float* node_emb = (const float*)d_in[2];
  const float* Wq = (const float*)d_in[3];
  const float* Wk = (const float*)d_in[4];
  const float* Wv = (const float*)d_in[5];
  const float* Wo = (const float*)d_in[6];
  const float* bo = (const float*)d_in[7];
  const float* eb = (const float*)d_in[8];
  const float* W1 = (const float*)d_in[9];
  const float* b1 = (const float*)d_in[10];
  const float* W2 = (const float*)d_in[11];
  const float* b2 = (const float*)d_in[12];
  const float* g1 = (const float*)d_in[13];
  const float* be1 = (const float*)d_in[14];
  const float* g2 = (const float*)d_in[15];
  const float* be2 = (const float*)d_in[16];
  const float* Wr = (const float*)d_in[17];
  const float* br = (const float*)d_in[18];
  float* out = (float*)d_out;

  // workspace layout
  float* x = (float*)d_ws;                       // N*D fp32
  float* Opart = x + (size_t)N * D;              // JC*N*D fp32
  float* lpart = Opart + (size_t)JC * N * D;     // JC*N*H
  float* ppool = lpart + (size_t)JC * N * H;     // 128*512
  float* WrT = ppool + 128 * 512;                // 256*512 fp32
  unsigned short* xb = (unsigned short*)(WrT + 256 * 512);
  unsigned short* qb = xb + (size_t)N * D;
  unsigned short* kb = qb + (size_t)N * D;
  unsigned short* vtb = kb + (size_t)N * D;      // (D, N) head-major d
  unsigned short* hb = vtb + (size_t)N * D;      // N*DFF
  unsigned short* wqkvb = hb + (size_t)N * DFF;  // L x (768, 256)
  unsigned short* wob = wqkvb + (size_t)L * 768 * D;
  unsigned short* w1b = wob + (size_t)L * D * D;
  unsigned short* w2b = w1b + (size_t)L * DFF * D;
  unsigned int* e8 = (unsigned int*)(w2b + (size_t)L * D * DFF);  // N*N bytes

  k_setup<<<7296, 256, 0, stream>>>(eidx, e8, Wq, Wk, Wv, Wo, W1, W2, Wr,
                                    wqkvb, wob, w1b, w2b, WrT);
  k_embed_qkv<<<128, 512, 0, stream>>>(node_types, node_emb, wqkvb, x, qb, kb, vtb);

  for (int l = 0; l < L; ++l) {
    k_attn<<<dim3(N / 32, JC), 512, 0, stream>>>(qb, kb, vtb, e8,
                                                 eb + (size_t)l * NEDGE * H,
                                                 Opart, lpart);
    k_opln1<<<N / 16, 512, 0, stream>>>(Opart, lpart,
                                        wob + (size_t)l * D * D, bo + (size_t)l * D,
                                        g1 + (size_t)l * D, be1 + (size_t)l * D, x, xb);
    k_mm<<<dim3(DFF / 64, N / 64, 1), 256, 0, stream>>>(
        xb, w1b + (size_t)l * DFF * D, DFF, D, D, b1 + (size_t)l * DFF, 1,
        (float*)nullptr, hb);
    k_ffn2ln<<<N / 16, 512, 0, stream>>>(
        hb, w2b + (size_t)l * D * DFF, b2 + (size_t)l * D,
        g2 + (size_t)l * D, be2 + (size_t)l * D, x, xb,
        (l == L - 1) ? ppool : nullptr);
    if (l < L - 1) {
      k_mm_qkv<<<dim3(768 / 64, N / 64), 256, 0, stream>>>(
          xb, wqkvb + (size_t)(l + 1) * 768 * D, qb, kb, vtb);
    }
  }

  k_pool2<<<1, 256, 0, stream>>>(ppool, WrT, br, out);
}